// Round 1
// baseline (2414.780 us; speedup 1.0000x reference)
//
#include <hip/hip_runtime.h>
#include <hip/hip_bf16.h>
#include <math.h>

// ---------------------------------------------------------------------------
// ELAN + SwinV2 block, fp32 baseline.
// Geometry: B=4, C_IN=128, H=W=128, DIM=256, WS=8, HEADS=8, HEAD_DIM=32.
// P = B*H*W = 65536 pixels; 1024 windows of 64 tokens.
// ---------------------------------------------------------------------------

#define PIX 65536
#define HW 16384

__device__ __forceinline__ float silu_f(float y) { return y / (1.f + expf(-y)); }

// ---------------- weight repack: wr_blk[(c*9+t)*64+oc], wr_stem[g][c*64+oc],
// ---------------- qkv_wt[c*768+row] ----------------------------------------
__global__ __launch_bounds__(256) void repack_kernel(
    const float* __restrict__ w_blk, const float* __restrict__ w_stem,
    const float* __restrict__ qkv_w, float* __restrict__ wrb,
    float* __restrict__ wrs, float* __restrict__ qwt) {
  int idx = blockIdx.x * 256 + threadIdx.x;
  if (idx < 147456) {
    int conv = idx / 36864, rr = idx % 36864;
    int oc = rr & 63, ct = rr >> 6;
    int c = ct / 9, t = ct % 9;
    wrb[idx] = w_blk[(size_t)conv * 36864 + oc * 576 + c * 9 + t];
  } else if (idx < 147456 + 16384) {
    int j = idx - 147456;
    int g = j >> 13, rr = j & 8191;
    int oc = rr & 63, c = rr >> 6;
    wrs[j] = w_stem[g * 8192 + oc * 128 + c];
  } else if (idx < 147456 + 16384 + 196608) {
    int j = idx - 147456 - 16384;
    int c = j / 768, row = j % 768;
    qwt[j] = qkv_w[row * 256 + c];
  }
}

// ---------------- continuous position bias MLP ------------------------------
__global__ __launch_bounds__(512) void cpb_mlp_kernel(
    const float* __restrict__ w1, const float* __restrict__ b1,
    const float* __restrict__ w2, float* __restrict__ pre) {
  __shared__ float hb[512];
  int t = blockIdx.x, j = threadIdx.x;
  int i = t / 15, jj = t % 15;
  float c0 = (float)(i - 7) * (8.f / 7.f);
  float c1 = (float)(jj - 7) * (8.f / 7.f);
  float s0 = (c0 > 0.f) ? 1.f : ((c0 < 0.f) ? -1.f : 0.f);
  float s1 = (c1 > 0.f) ? 1.f : ((c1 < 0.f) ? -1.f : 0.f);
  float t0 = s0 * log2f(fabsf(c0) + 1.f) * (1.f / 3.f);
  float t1 = s1 * log2f(fabsf(c1) + 1.f) * (1.f / 3.f);
  float h = t0 * w1[j * 2] + t1 * w1[j * 2 + 1] + b1[j];
  hb[j] = fmaxf(h, 0.f);
  __syncthreads();
  if (j < 8) {
    float s = 0.f;
    for (int k = 0; k < 512; ++k) s += hb[k] * w2[j * 512 + k];
    pre[t * 8 + j] = s;
  }
}

__global__ __launch_bounds__(256) void cpb_expand_kernel(
    const float* __restrict__ pre, float* __restrict__ bias_full) {
  int idx = blockIdx.x * 256 + threadIdx.x;  // 4096 (n,m) pairs
  int n = idx >> 6, m = idx & 63;
  int di = (n >> 3) - (m >> 3) + 7;
  int dj = (n & 7) - (m & 7) + 7;
  int ti = di * 15 + dj;
#pragma unroll
  for (int h = 0; h < 8; ++h) {
    float v = pre[ti * 8 + h];
    bias_full[h * 4096 + idx] = 16.f / (1.f + expf(-v));
  }
}

// ---------------- stem 1x1 convs (main + short) -----------------------------
__global__ __launch_bounds__(256) void stem_kernel(
    const float* __restrict__ x, const float* __restrict__ wrs,
    const float* __restrict__ s_stem, const float* __restrict__ b_stem,
    float* __restrict__ outm, float* __restrict__ outs) {
  __shared__ float xs[128][64];
  int tid = threadIdx.x;
  int b = blockIdx.x >> 8;
  int hw0 = (blockIdx.x & 255) << 6;
  int px = tid & 63;
  int q = __builtin_amdgcn_readfirstlane(tid >> 6);
  for (int e = tid; e < 8192; e += 256) {
    int c = e >> 6, p = e & 63;
    xs[c][p] = x[(size_t)(b * 128 + c) * HW + hw0 + p];
  }
  __syncthreads();
  float am[16] = {}, as2[16] = {};
  for (int c = 0; c < 128; ++c) {
    float xv = xs[c][px];
    const float* wm = wrs + c * 64 + q * 16;
    const float* wsh = wrs + 8192 + c * 64 + q * 16;
#pragma unroll
    for (int k = 0; k < 16; ++k) am[k] += xv * wm[k];
#pragma unroll
    for (int k = 0; k < 16; ++k) as2[k] += xv * wsh[k];
  }
#pragma unroll
  for (int k = 0; k < 16; ++k) {
    int oc = q * 16 + k;
    float ym = am[k] * s_stem[oc] + b_stem[oc];
    outm[(size_t)(b * 64 + oc) * HW + hw0 + px] = silu_f(ym);
    float ys = as2[k] * s_stem[64 + oc] + b_stem[64 + oc];
    outs[(size_t)(b * 64 + oc) * HW + hw0 + px] = silu_f(ys);
  }
}

// ---------------- 3x3 conv (64->64, pad 1) + BN-fold + SiLU -----------------
__global__ __launch_bounds__(256) void conv3x3_kernel(
    const float* __restrict__ in, float* __restrict__ outp,
    const float* __restrict__ wr, const float* __restrict__ sc,
    const float* __restrict__ bi) {
  __shared__ float ins[8][18][18];
  int tid = threadIdx.x;
  int bx = blockIdx.x, by = blockIdx.y, b = blockIdx.z;
  int px = tid & 15, py = tid >> 4;
  float acc[64] = {};
  for (int c0 = 0; c0 < 64; c0 += 8) {
    __syncthreads();
    for (int e = tid; e < 2592; e += 256) {
      int c = e / 324, r = (e % 324) / 18, cl = e % 18;
      int gh = by * 16 + r - 1, gw = bx * 16 + cl - 1;
      float v = 0.f;
      if (gh >= 0 && gh < 128 && gw >= 0 && gw < 128)
        v = in[(size_t)(b * 64 + c0 + c) * HW + gh * 128 + gw];
      ins[c][r][cl] = v;
    }
    __syncthreads();
    for (int c = 0; c < 8; ++c) {
#pragma unroll
      for (int t = 0; t < 9; ++t) {
        int kh = t / 3, kw = t % 3;
        float xv = ins[c][py + kh][px + kw];
        const float* wb = wr + ((c0 + c) * 9 + t) * 64;
#pragma unroll
        for (int oc = 0; oc < 64; ++oc) acc[oc] += xv * wb[oc];
      }
    }
  }
  int h = by * 16 + py, w = bx * 16 + px;
#pragma unroll
  for (int oc = 0; oc < 64; ++oc) {
    float y = acc[oc] * sc[oc] + bi[oc];
    outp[(size_t)(b * 64 + oc) * HW + h * 128 + w] = silu_f(y);
  }
}

// ---------------- concat 4x NCHW(64) slices -> NHWC e[P][256] ---------------
__global__ __launch_bounds__(256) void pack_kernel(
    const float* __restrict__ s0, const float* __restrict__ s1,
    const float* __restrict__ s2, const float* __restrict__ s3,
    float* __restrict__ e) {
  __shared__ float tl[64][65];
  int bid = blockIdx.x;
  int src = bid >> 10;
  int t = bid & 1023;
  int b = t >> 8, hw0 = (t & 255) << 6;
  const float* sp = src == 0 ? s0 : src == 1 ? s1 : src == 2 ? s2 : s3;
  int cbase = src << 6;
  int tid = threadIdx.x;
  for (int ee = tid; ee < 4096; ee += 256) {
    int oc = ee >> 6, p = ee & 63;
    tl[oc][p] = sp[(size_t)(b * 64 + oc) * HW + hw0 + p];
  }
  __syncthreads();
  for (int ee = tid; ee < 4096; ee += 256) {
    int p = ee >> 6, oc = ee & 63;
    e[(size_t)(b * HW + hw0 + p) * 256 + cbase + oc] = tl[oc][p];
  }
}

// ---------------- window attention: 1 block = 1 window x 4 heads ------------
// qkv computed in-block from e (repacked qkv_wt), cosine attn, online softmax.
__global__ __launch_bounds__(256) void attn_kernel(
    const float* __restrict__ e, const float* __restrict__ qwt,
    const float* __restrict__ qkv_b, const float* __restrict__ logit_scale,
    const float* __restrict__ bias_full, float* __restrict__ ao) {
  __shared__ float ebuf[256][66];      // [c][token], padded
  __shared__ float kn_s[4][64][33];    // normalized K
  __shared__ float v_s[4][64][33];
  int tid = threadIdx.x;
  int wid = blockIdx.x >> 1, half = blockIdx.x & 1;
  int b = wid >> 8, wh = (wid >> 4) & 15, ww = wid & 15;
  int hl = tid >> 6, n = tid & 63;
  int head = half * 4 + hl;
  int pixbase = (b << 14) + ((wh * 8) << 7) + ww * 8;
  for (int tok = 0; tok < 64; ++tok) {
    int p = pixbase + ((tok >> 3) << 7) + (tok & 7);
    ebuf[tid][tok] = e[(size_t)p * 256 + tid];
  }
  __syncthreads();
  int head_u = __builtin_amdgcn_readfirstlane(head);
  float accq[32], acck[32], accv[32];
#pragma unroll
  for (int d = 0; d < 32; ++d) {
    accq[d] = qkv_b[head_u * 32 + d];
    acck[d] = qkv_b[256 + head_u * 32 + d];
    accv[d] = qkv_b[512 + head_u * 32 + d];
  }
  for (int c = 0; c < 256; ++c) {
    float ev = ebuf[c][n];
    const float* wr = qwt + c * 768 + head_u * 32;
#pragma unroll
    for (int d = 0; d < 32; ++d) accq[d] += ev * wr[d];
#pragma unroll
    for (int d = 0; d < 32; ++d) acck[d] += ev * wr[256 + d];
#pragma unroll
    for (int d = 0; d < 32; ++d) accv[d] += ev * wr[512 + d];
  }
  float sq = 0.f, sk = 0.f;
#pragma unroll
  for (int d = 0; d < 32; ++d) { sq += accq[d] * accq[d]; sk += acck[d] * acck[d]; }
  float rq = 1.f / fmaxf(sqrtf(sq), 1e-12f);
  float rk = 1.f / fmaxf(sqrtf(sk), 1e-12f);
#pragma unroll
  for (int d = 0; d < 32; ++d) {
    accq[d] *= rq;
    kn_s[hl][n][d] = acck[d] * rk;
    v_s[hl][n][d] = accv[d];
  }
  __syncthreads();
  float scale = expf(fminf(logit_scale[head], 4.6051701860f));
  const float* brow = bias_full + head * 4096 + n * 64;
  float mx = -3.4e38f, denom = 0.f;
  float acc[32];
#pragma unroll
  for (int d = 0; d < 32; ++d) acc[d] = 0.f;
  for (int m = 0; m < 64; ++m) {
    float s = 0.f;
#pragma unroll
    for (int d = 0; d < 32; ++d) s += accq[d] * kn_s[hl][m][d];
    float l = s * scale + brow[m];
    float mn = fmaxf(mx, l);
    float sf = expf(mx - mn);
    float pe = expf(l - mn);
    denom = denom * sf + pe;
#pragma unroll
    for (int d = 0; d < 32; ++d) acc[d] = acc[d] * sf + pe * v_s[hl][m][d];
    mx = mn;
  }
  float inv = 1.f / denom;
  size_t tg = (size_t)(wid * 64 + n) * 256 + head * 32;
#pragma unroll
  for (int d = 0; d < 32; ++d) ao[tg + d] = acc[d] * inv;
}

// ---------------- generic tiled GEMM: C[M,256] = act(A[M,256] @ W[256,256]^T + b)
__global__ __launch_bounds__(256) void gemm_kernel(
    const float* __restrict__ A, const float* __restrict__ W,
    const float* __restrict__ bias, float* __restrict__ C, int act) {
  __shared__ float As[16][65];
  __shared__ float Ws[16][65];
  int tid = threadIdx.x;
  int m0 = blockIdx.x * 64;
  int n0 = blockIdx.y * 64;
  int tx = tid & 15, ty = tid >> 4;
  float acc[4][4] = {};
  for (int k0 = 0; k0 < 256; k0 += 16) {
#pragma unroll
    for (int i = 0; i < 4; ++i) {
      int e = tid + i * 256;
      int k = e & 15, m = e >> 4;
      As[k][m] = A[(size_t)(m0 + m) * 256 + k0 + k];
      Ws[k][m] = W[(size_t)(n0 + m) * 256 + k0 + k];
    }
    __syncthreads();
#pragma unroll
    for (int k = 0; k < 16; ++k) {
      float a[4], bb[4];
#pragma unroll
      for (int i = 0; i < 4; ++i) a[i] = As[k][ty * 4 + i];
#pragma unroll
      for (int j = 0; j < 4; ++j) bb[j] = Ws[k][tx * 4 + j];
#pragma unroll
      for (int i = 0; i < 4; ++i)
#pragma unroll
        for (int j = 0; j < 4; ++j) acc[i][j] += a[i] * bb[j];
    }
    __syncthreads();
  }
#pragma unroll
  for (int i = 0; i < 4; ++i) {
    int m = m0 + ty * 4 + i;
#pragma unroll
    for (int j = 0; j < 4; ++j) {
      int nn = n0 + tx * 4 + j;
      float v = acc[i][j] + bias[nn];
      if (act == 1) v = 0.5f * v * (1.f + erff(v * 0.70710678118654752f));
      C[(size_t)m * 256 + nn] = v;
    }
  }
}

// ---------------- LayerNorm(ln_in) * g + b + res -> dst ---------------------
// remap=1: ln_in is token-major (window order), res/dst pixel-major.
__global__ __launch_bounds__(256) void ln_res_kernel(
    const float* __restrict__ ln_in, const float* __restrict__ res,
    float* __restrict__ dst, const float* __restrict__ g,
    const float* __restrict__ bb, int remap) {
  int t = blockIdx.x, c = threadIdx.x;
  int p;
  if (remap) {
    int wid = t >> 6, n = t & 63;
    int b = wid >> 8, wh = (wid >> 4) & 15, ww = wid & 15;
    p = (b << 14) + ((wh * 8 + (n >> 3)) << 7) + ww * 8 + (n & 7);
  } else {
    p = t;
  }
  float v = ln_in[(size_t)t * 256 + c];
  float s1 = v, s2 = v * v;
#pragma unroll
  for (int o = 32; o > 0; o >>= 1) {
    s1 += __shfl_down(s1, o);
    s2 += __shfl_down(s2, o);
  }
  __shared__ float red[8];
  if ((c & 63) == 0) { red[c >> 6] = s1; red[4 + (c >> 6)] = s2; }
  __syncthreads();
  s1 = red[0] + red[1] + red[2] + red[3];
  s2 = red[4] + red[5] + red[6] + red[7];
  float mean = s1 * (1.f / 256.f);
  float var = s2 * (1.f / 256.f) - mean * mean;
  float rs = rsqrtf(var + 1e-5f);
  float ln = (v - mean) * rs * g[c] + bb[c];
  dst[(size_t)p * 256 + c] = res[(size_t)p * 256 + c] + ln;
}

// ---------------- NHWC [P][256] -> NCHW output ------------------------------
__global__ __launch_bounds__(256) void transpose_kernel(
    const float* __restrict__ F, float* __restrict__ outp) {
  __shared__ float tl[64][65];
  int bid = blockIdx.x;
  int b = bid >> 10;
  int r = bid & 1023;
  int ct = r >> 8, hwt = r & 255;
  int c0 = ct << 6, hw0 = hwt << 6;
  int tid = threadIdx.x;
  for (int e = tid; e < 4096; e += 256) {
    int p = e >> 6, cc = e & 63;
    tl[p][cc] = F[(size_t)(b * HW + hw0 + p) * 256 + c0 + cc];
  }
  __syncthreads();
  for (int e = tid; e < 4096; e += 256) {
    int cc = e >> 6, p = e & 63;
    outp[(size_t)(b * 256 + c0 + cc) * HW + hw0 + p] = tl[p][cc];
  }
}

// ---------------------------------------------------------------------------
extern "C" void kernel_launch(void* const* d_in, const int* in_sizes, int n_in,
                              void* d_out, int out_size, void* d_ws, size_t ws_size,
                              hipStream_t stream) {
  const float* x        = (const float*)d_in[0];
  const float* w_stem   = (const float*)d_in[1];
  const float* s_stem   = (const float*)d_in[2];
  const float* b_stem   = (const float*)d_in[3];
  const float* w_blk    = (const float*)d_in[4];
  const float* s_blk    = (const float*)d_in[5];
  const float* b_blk    = (const float*)d_in[6];
  const float* norm1_g  = (const float*)d_in[7];
  const float* norm1_b  = (const float*)d_in[8];
  const float* qkv_w    = (const float*)d_in[9];
  const float* qkv_b    = (const float*)d_in[10];
  const float* proj_w   = (const float*)d_in[11];
  const float* proj_b   = (const float*)d_in[12];
  const float* logit_sc = (const float*)d_in[13];
  const float* cpb_w1   = (const float*)d_in[14];
  const float* cpb_b1   = (const float*)d_in[15];
  const float* cpb_w2   = (const float*)d_in[16];
  const float* norm2_g  = (const float*)d_in[17];
  const float* norm2_b  = (const float*)d_in[18];
  const float* mlp_w1   = (const float*)d_in[19];
  const float* mlp_b1   = (const float*)d_in[20];
  const float* mlp_w2   = (const float*)d_in[21];
  const float* mlp_b2   = (const float*)d_in[22];
  float* out = (float*)d_out;
  float* ws = (float*)d_ws;

  // workspace layout (floats)
  float* E   = ws;                       // 16,777,216  e -> S (in place)
  float* R1  = ws + 16777216;            // 16,777,216  conv bufs -> ao -> H -> F
  float* R2  = ws + 33554432;            // 16,777,216  conv B/D -> attn_tok -> H2
  float* WRB = ws + 50331648;            // 147,456 repacked blk weights
  float* WRS = WRB + 147456;             // 16,384 repacked stem weights
  float* QWT = WRS + 16384;              // 196,608 qkv_w transposed [c][row]
  float* BPRE = QWT + 196608;            // 2048 (225*8 used)
  float* BFULL = BPRE + 2048;            // 32,768 bias[8][64][64]

  float* convA = R1;                     // x_main  NCHW
  float* convS = R1 + 4194304;           // x_short NCHW
  float* convC1 = R1 + 8388608;          // outs[0]
  float* convE3 = R1 + 12582912;         // outs[1]
  float* convB = R2;                     // ping
  float* convD = R2 + 4194304;           // pong

  (void)in_sizes; (void)n_in; (void)out_size; (void)ws_size;

  repack_kernel<<<1408, 256, 0, stream>>>(w_blk, w_stem, qkv_w, WRB, WRS, QWT);
  cpb_mlp_kernel<<<225, 512, 0, stream>>>(cpb_w1, cpb_b1, cpb_w2, BPRE);
  cpb_expand_kernel<<<16, 256, 0, stream>>>(BPRE, BFULL);

  stem_kernel<<<1024, 256, 0, stream>>>(x, WRS, s_stem, b_stem, convA, convS);
  dim3 cgrid(8, 8, 4);
  conv3x3_kernel<<<cgrid, 256, 0, stream>>>(convA, convB, WRB, s_blk, b_blk);
  conv3x3_kernel<<<cgrid, 256, 0, stream>>>(convB, convC1, WRB + 36864, s_blk + 64, b_blk + 64);
  conv3x3_kernel<<<cgrid, 256, 0, stream>>>(convC1, convD, WRB + 73728, s_blk + 128, b_blk + 128);
  conv3x3_kernel<<<cgrid, 256, 0, stream>>>(convD, convE3, WRB + 110592, s_blk + 192, b_blk + 192);

  pack_kernel<<<4096, 256, 0, stream>>>(convE3, convC1, convA, convS, E);

  attn_kernel<<<2048, 256, 0, stream>>>(E, QWT, qkv_b, logit_sc, BFULL, R1);

  dim3 ggrid(1024, 4);
  gemm_kernel<<<ggrid, 256, 0, stream>>>(R1, proj_w, proj_b, R2, 0);     // proj -> attn_tok
  ln_res_kernel<<<65536, 256, 0, stream>>>(R2, E, E, norm1_g, norm1_b, 1); // S = e + LN(attn)
  gemm_kernel<<<ggrid, 256, 0, stream>>>(E, mlp_w1, mlp_b1, R1, 1);      // H = gelu(...)
  gemm_kernel<<<ggrid, 256, 0, stream>>>(R1, mlp_w2, mlp_b2, R2, 0);     // H2
  ln_res_kernel<<<65536, 256, 0, stream>>>(R2, E, R1, norm2_g, norm2_b, 0); // F = S + LN(H2)
  transpose_kernel<<<4096, 256, 0, stream>>>(R1, out);
}

// Round 2
// 1289.048 us; speedup vs baseline: 1.8733x; 1.8733x over previous
//
#include <hip/hip_runtime.h>
#include <hip/hip_bf16.h>
#include <math.h>

// ---------------------------------------------------------------------------
// ELAN + SwinV2: fp32 convs, bf16-MFMA GEMMs (qkv/proj/mlp), fused window attn.
// B=4, C_IN=128, H=W=128, DIM=256, WS=8, HEADS=8, HEAD_DIM=32.
// ---------------------------------------------------------------------------

#define HW 16384
typedef unsigned int u32;
typedef unsigned short u16;
typedef __attribute__((ext_vector_type(8))) short short8;   // bf16x8 MFMA frag
typedef __attribute__((ext_vector_type(4))) float floatx4;  // f32x4 acc frag

__device__ __forceinline__ float silu_f(float y) { return y / (1.f + expf(-y)); }
__device__ __forceinline__ float bflo(u32 u) { return __uint_as_float(u << 16); }
__device__ __forceinline__ float bfhi(u32 u) { return __uint_as_float(u & 0xffff0000u); }
__device__ __forceinline__ u16 f2bf(float x) {
  u32 u = __float_as_uint(x);
  u += 0x7fffu + ((u >> 16) & 1u);
  return (u16)(u >> 16);
}
__device__ __forceinline__ u32 pack2(float a, float b) {
  return (u32)f2bf(a) | ((u32)f2bf(b) << 16);
}

#define GLDS16(gp, lp)                                           \
  __builtin_amdgcn_global_load_lds(                              \
      (const __attribute__((address_space(1))) void*)(gp),       \
      (__attribute__((address_space(3))) void*)(lp), 16, 0, 0)

// ---------------- conv weight repack --------------------------------------
__global__ __launch_bounds__(256) void repack_kernel(
    const float* __restrict__ w_blk, const float* __restrict__ w_stem,
    float* __restrict__ wrb, float* __restrict__ wrs) {
  int idx = blockIdx.x * 256 + threadIdx.x;
  if (idx < 147456) {
    int conv = idx / 36864, rr = idx % 36864;
    int oc = rr & 63, ct = rr >> 6;
    int c = ct / 9, t = ct % 9;
    wrb[idx] = w_blk[(size_t)conv * 36864 + oc * 576 + c * 9 + t];
  } else if (idx < 147456 + 16384) {
    int j = idx - 147456;
    int g = j >> 13, rr = j & 8191;
    int oc = rr & 63, c = rr >> 6;
    wrs[j] = w_stem[g * 8192 + oc * 128 + c];
  }
}

// ---------------- generic fp32 -> bf16 cast (weights) ----------------------
__global__ __launch_bounds__(256) void castw_kernel(
    const float* __restrict__ in, u16* __restrict__ outp, int n) {
  int i = blockIdx.x * 256 + threadIdx.x;
  if (i < n) outp[i] = f2bf(in[i]);
}

// ---------------- continuous position bias MLP -----------------------------
__global__ __launch_bounds__(512) void cpb_mlp_kernel(
    const float* __restrict__ w1, const float* __restrict__ b1,
    const float* __restrict__ w2, float* __restrict__ pre) {
  __shared__ float hb[512];
  int t = blockIdx.x, j = threadIdx.x;
  int i = t / 15, jj = t % 15;
  float c0 = (float)(i - 7) * (8.f / 7.f);
  float c1 = (float)(jj - 7) * (8.f / 7.f);
  float s0 = (c0 > 0.f) ? 1.f : ((c0 < 0.f) ? -1.f : 0.f);
  float s1 = (c1 > 0.f) ? 1.f : ((c1 < 0.f) ? -1.f : 0.f);
  float t0 = s0 * log2f(fabsf(c0) + 1.f) * (1.f / 3.f);
  float t1 = s1 * log2f(fabsf(c1) + 1.f) * (1.f / 3.f);
  float h = t0 * w1[j * 2] + t1 * w1[j * 2 + 1] + b1[j];
  hb[j] = fmaxf(h, 0.f);
  __syncthreads();
  if (j < 8) {
    float s = 0.f;
    for (int k = 0; k < 512; ++k) s += hb[k] * w2[j * 512 + k];
    pre[t * 8 + j] = s;
  }
}

// bias_t[h][m][n] (key-major so attn's per-m load is lane-coalesced over n)
__global__ __launch_bounds__(256) void cpb_expand_kernel(
    const float* __restrict__ pre, float* __restrict__ bias_t) {
  int idx = blockIdx.x * 256 + threadIdx.x;  // 4096 (m,n) pairs
  int m = idx >> 6, n = idx & 63;
  int di = (n >> 3) - (m >> 3) + 7;
  int dj = (n & 7) - (m & 7) + 7;
  int ti = di * 15 + dj;
#pragma unroll
  for (int h = 0; h < 8; ++h) {
    float v = pre[ti * 8 + h];
    bias_t[h * 4096 + idx] = 16.f / (1.f + expf(-v));
  }
}

// ---------------- stem 1x1 convs (main + short) -----------------------------
__global__ __launch_bounds__(256) void stem_kernel(
    const float* __restrict__ x, const float* __restrict__ wrs,
    const float* __restrict__ s_stem, const float* __restrict__ b_stem,
    float* __restrict__ outm, float* __restrict__ outs) {
  __shared__ float xs[128][64];
  int tid = threadIdx.x;
  int b = blockIdx.x >> 8;
  int hw0 = (blockIdx.x & 255) << 6;
  int px = tid & 63;
  int q = __builtin_amdgcn_readfirstlane(tid >> 6);
  for (int e = tid; e < 8192; e += 256) {
    int c = e >> 6, p = e & 63;
    xs[c][p] = x[(size_t)(b * 128 + c) * HW + hw0 + p];
  }
  __syncthreads();
  float am[16] = {}, as2[16] = {};
  for (int c = 0; c < 128; ++c) {
    float xv = xs[c][px];
    const float* wm = wrs + c * 64 + q * 16;
    const float* wsh = wrs + 8192 + c * 64 + q * 16;
#pragma unroll
    for (int k = 0; k < 16; ++k) am[k] += xv * wm[k];
#pragma unroll
    for (int k = 0; k < 16; ++k) as2[k] += xv * wsh[k];
  }
#pragma unroll
  for (int k = 0; k < 16; ++k) {
    int oc = q * 16 + k;
    float ym = am[k] * s_stem[oc] + b_stem[oc];
    outm[(size_t)(b * 64 + oc) * HW + hw0 + px] = silu_f(ym);
    float ys = as2[k] * s_stem[64 + oc] + b_stem[64 + oc];
    outs[(size_t)(b * 64 + oc) * HW + hw0 + px] = silu_f(ys);
  }
}

// ---------------- 3x3 conv (64->64, pad 1) + BN-fold + SiLU -----------------
__global__ __launch_bounds__(256) void conv3x3_kernel(
    const float* __restrict__ in, float* __restrict__ outp,
    const float* __restrict__ wr, const float* __restrict__ sc,
    const float* __restrict__ bi) {
  __shared__ float ins[8][18][18];
  int tid = threadIdx.x;
  int bx = blockIdx.x, by = blockIdx.y, b = blockIdx.z;
  int px = tid & 15, py = tid >> 4;
  float acc[64] = {};
  for (int c0 = 0; c0 < 64; c0 += 8) {
    __syncthreads();
    for (int e = tid; e < 2592; e += 256) {
      int c = e / 324, r = (e % 324) / 18, cl = e % 18;
      int gh = by * 16 + r - 1, gw = bx * 16 + cl - 1;
      float v = 0.f;
      if (gh >= 0 && gh < 128 && gw >= 0 && gw < 128)
        v = in[(size_t)(b * 64 + c0 + c) * HW + gh * 128 + gw];
      ins[c][r][cl] = v;
    }
    __syncthreads();
    for (int c = 0; c < 8; ++c) {
#pragma unroll
      for (int t = 0; t < 9; ++t) {
        int kh = t / 3, kw = t % 3;
        float xv = ins[c][py + kh][px + kw];
        const float* wb = wr + ((c0 + c) * 9 + t) * 64;
#pragma unroll
        for (int oc = 0; oc < 64; ++oc) acc[oc] += xv * wb[oc];
      }
    }
  }
  int h = by * 16 + py, w = bx * 16 + px;
#pragma unroll
  for (int oc = 0; oc < 64; ++oc) {
    float y = acc[oc] * sc[oc] + bi[oc];
    outp[(size_t)(b * 64 + oc) * HW + h * 128 + w] = silu_f(y);
  }
}

// ---------------- concat 4 NCHW slices -> NHWC e (fp32 + bf16) --------------
__global__ __launch_bounds__(256) void pack_kernel(
    const float* __restrict__ s0, const float* __restrict__ s1,
    const float* __restrict__ s2, const float* __restrict__ s3,
    float* __restrict__ e, u16* __restrict__ ebf) {
  __shared__ float tl[64][65];
  int bid = blockIdx.x;
  int src = bid >> 10;
  int t = bid & 1023;
  int b = t >> 8, hw0 = (t & 255) << 6;
  const float* sp = src == 0 ? s0 : src == 1 ? s1 : src == 2 ? s2 : s3;
  int cbase = src << 6;
  int tid = threadIdx.x;
  for (int ee = tid; ee < 4096; ee += 256) {
    int oc = ee >> 6, p = ee & 63;
    tl[oc][p] = sp[(size_t)(b * 64 + oc) * HW + hw0 + p];
  }
  __syncthreads();
  for (int ee = tid; ee < 4096; ee += 256) {
    int p = ee >> 6, oc = ee & 63;
    float v = tl[oc][p];
    size_t gi = (size_t)(b * HW + hw0 + p) * 256 + cbase + oc;
    e[gi] = v;
    ebf[gi] = f2bf(v);
  }
}

// ---------------- bf16 MFMA GEMM: C[M,N] = act(A[M,256] @ W[N,256]^T + b) ----
// A,W bf16 row-major K=256; C bf16. Tile 128x64, BK=64, XOR-swizzled LDS.
__global__ __launch_bounds__(256, 4) void gemm_bf16_kernel(
    const u16* __restrict__ A, const u16* __restrict__ W,
    const float* __restrict__ bias, u16* __restrict__ C, int N, int act) {
  __shared__ u16 As[128 * 64];
  __shared__ u16 Ws[64 * 64];
  int tid = threadIdx.x;
  int wv = tid >> 6, lane = tid & 63;
  int m0 = blockIdx.x * 128, n0 = blockIdx.y * 64;
  floatx4 zz = {0.f, 0.f, 0.f, 0.f};
  floatx4 acc[2][4];
#pragma unroll
  for (int i = 0; i < 2; ++i)
#pragma unroll
    for (int j = 0; j < 4; ++j) acc[i][j] = zz;
  int lr = lane >> 3, ls = lane & 7;
  for (int k0 = 0; k0 < 256; k0 += 64) {
#pragma unroll
    for (int i = 0; i < 4; ++i) {
      int ci = wv * 4 + i;
      int r = ci * 8 + lr;
      int cc = ls ^ (r & 7);
      GLDS16(A + (size_t)(m0 + r) * 256 + k0 + cc * 8, As + ci * 512);
    }
#pragma unroll
    for (int i = 0; i < 2; ++i) {
      int ci = wv * 2 + i;
      int r = ci * 8 + lr;
      int cc = ls ^ (r & 7);
      GLDS16(W + (size_t)(n0 + r) * 256 + k0 + cc * 8, Ws + ci * 512);
    }
    __syncthreads();
#pragma unroll
    for (int kk = 0; kk < 2; ++kk) {
      int g = kk * 4 + (lane >> 4);
      short8 a0, a1, b0, b1, b2, b3;
      {
        int row = wv * 32 + (lane & 15);
        a0 = *(const short8*)&As[row * 64 + (g ^ (row & 7)) * 8];
        int row2 = row + 16;
        a1 = *(const short8*)&As[row2 * 64 + (g ^ (row2 & 7)) * 8];
      }
      {
        int col = lane & 15;
        b0 = *(const short8*)&Ws[col * 64 + (g ^ (col & 7)) * 8];
        int c1 = col + 16;
        b1 = *(const short8*)&Ws[c1 * 64 + (g ^ (c1 & 7)) * 8];
        int c2 = col + 32;
        b2 = *(const short8*)&Ws[c2 * 64 + (g ^ (c2 & 7)) * 8];
        int c3 = col + 48;
        b3 = *(const short8*)&Ws[c3 * 64 + (g ^ (c3 & 7)) * 8];
      }
      acc[0][0] = __builtin_amdgcn_mfma_f32_16x16x32_bf16(a0, b0, acc[0][0], 0, 0, 0);
      acc[0][1] = __builtin_amdgcn_mfma_f32_16x16x32_bf16(a0, b1, acc[0][1], 0, 0, 0);
      acc[0][2] = __builtin_amdgcn_mfma_f32_16x16x32_bf16(a0, b2, acc[0][2], 0, 0, 0);
      acc[0][3] = __builtin_amdgcn_mfma_f32_16x16x32_bf16(a0, b3, acc[0][3], 0, 0, 0);
      acc[1][0] = __builtin_amdgcn_mfma_f32_16x16x32_bf16(a1, b0, acc[1][0], 0, 0, 0);
      acc[1][1] = __builtin_amdgcn_mfma_f32_16x16x32_bf16(a1, b1, acc[1][1], 0, 0, 0);
      acc[1][2] = __builtin_amdgcn_mfma_f32_16x16x32_bf16(a1, b2, acc[1][2], 0, 0, 0);
      acc[1][3] = __builtin_amdgcn_mfma_f32_16x16x32_bf16(a1, b3, acc[1][3], 0, 0, 0);
    }
    __syncthreads();
  }
  int rbase = wv * 32 + ((lane >> 4) << 2);
  int cbase = lane & 15;
#pragma unroll
  for (int mi = 0; mi < 2; ++mi) {
#pragma unroll
    for (int nj = 0; nj < 4; ++nj) {
      int col = n0 + nj * 16 + cbase;
      float bv = bias[col];
#pragma unroll
      for (int r = 0; r < 4; ++r) {
        int row = m0 + rbase + mi * 16 + r;
        float v = acc[mi][nj][r] + bv;
        if (act) v = 0.5f * v * (1.f + erff(v * 0.70710678118654752f));
        C[(size_t)row * N + col] = f2bf(v);
      }
    }
  }
}

// ---------------- window attention: block = window, wave = head --------------
__global__ __launch_bounds__(512, 4) void attn_kernel(
    const u16* __restrict__ qkv, const float* __restrict__ logit_scale,
    const float* __restrict__ bias_t, u16* __restrict__ ao) {
  __shared__ uint4 kn_s[8][4][64];  // [head][slot(8 bf16)][token]
  __shared__ uint4 v_s[8][4][64];
  int tid = threadIdx.x;
  int h = __builtin_amdgcn_readfirstlane(tid >> 6);
  int n = tid & 63;
  int wid = blockIdx.x;
  int b = wid >> 8, wh = (wid >> 4) & 15, ww = wid & 15;
  int p = (b << 14) + ((wh * 8 + (n >> 3)) << 7) + ww * 8 + (n & 7);
  const u32* qp = (const u32*)(qkv + (size_t)p * 768 + h * 32);

  float scale = __expf(fminf(logit_scale[h], 4.6051701860f));
  float qf[32];
#pragma unroll
  for (int i = 0; i < 16; ++i) {
    u32 u = qp[i];
    qf[2 * i] = bflo(u);
    qf[2 * i + 1] = bfhi(u);
  }
  float sq = 0.f;
#pragma unroll
  for (int d = 0; d < 32; ++d) sq += qf[d] * qf[d];
  float rq = scale / fmaxf(sqrtf(sq), 1e-12f);
#pragma unroll
  for (int d = 0; d < 32; ++d) qf[d] *= rq;

  {  // K: load, normalize, stage
    float kf[32];
#pragma unroll
    for (int i = 0; i < 16; ++i) {
      u32 u = qp[128 + i];
      kf[2 * i] = bflo(u);
      kf[2 * i + 1] = bfhi(u);
    }
    float sk = 0.f;
#pragma unroll
    for (int d = 0; d < 32; ++d) sk += kf[d] * kf[d];
    float rk = 1.f / fmaxf(sqrtf(sk), 1e-12f);
#pragma unroll
    for (int sl = 0; sl < 4; ++sl) {
      uint4 w4;
      w4.x = pack2(kf[sl * 8 + 0] * rk, kf[sl * 8 + 1] * rk);
      w4.y = pack2(kf[sl * 8 + 2] * rk, kf[sl * 8 + 3] * rk);
      w4.z = pack2(kf[sl * 8 + 4] * rk, kf[sl * 8 + 5] * rk);
      w4.w = pack2(kf[sl * 8 + 6] * rk, kf[sl * 8 + 7] * rk);
      kn_s[h][sl][n] = w4;
    }
  }
  {  // V: stage as-is
#pragma unroll
    for (int sl = 0; sl < 4; ++sl) {
      uint4 w4;
      w4.x = qp[256 + sl * 4 + 0];
      w4.y = qp[256 + sl * 4 + 1];
      w4.z = qp[256 + sl * 4 + 2];
      w4.w = qp[256 + sl * 4 + 3];
      // repack u32 pair-order is already (lo,hi) little-endian
      v_s[h][sl][n] = w4;
    }
  }
  __syncthreads();

  const float* brow = bias_t + h * 4096 + n;
  float bcur = brow[0];
  float mx = -3.4e38f, den = 0.f;
  float acc[32];
#pragma unroll
  for (int d = 0; d < 32; ++d) acc[d] = 0.f;

#define DOT8(uu, base)                                             \
  s += bflo(uu.x) * qf[base + 0] + bfhi(uu.x) * qf[base + 1] +     \
       bflo(uu.y) * qf[base + 2] + bfhi(uu.y) * qf[base + 3] +     \
       bflo(uu.z) * qf[base + 4] + bfhi(uu.z) * qf[base + 5] +     \
       bflo(uu.w) * qf[base + 6] + bfhi(uu.w) * qf[base + 7];
#define PV8(vv, base)                                              \
  acc[base + 0] = acc[base + 0] * sf + pe * bflo(vv.x);            \
  acc[base + 1] = acc[base + 1] * sf + pe * bfhi(vv.x);            \
  acc[base + 2] = acc[base + 2] * sf + pe * bflo(vv.y);            \
  acc[base + 3] = acc[base + 3] * sf + pe * bfhi(vv.y);            \
  acc[base + 4] = acc[base + 4] * sf + pe * bflo(vv.z);            \
  acc[base + 5] = acc[base + 5] * sf + pe * bfhi(vv.z);            \
  acc[base + 6] = acc[base + 6] * sf + pe * bflo(vv.w);            \
  acc[base + 7] = acc[base + 7] * sf + pe * bfhi(vv.w);

  for (int m = 0; m < 64; ++m) {
    float bnx = (m < 63) ? brow[(m + 1) * 64] : 0.f;
    uint4 k0 = kn_s[h][0][m];
    uint4 k1 = kn_s[h][1][m];
    uint4 k2 = kn_s[h][2][m];
    uint4 k3 = kn_s[h][3][m];
    float s = 0.f;
    DOT8(k0, 0) DOT8(k1, 8) DOT8(k2, 16) DOT8(k3, 24)
    float l = s + bcur;
    float mn = fmaxf(mx, l);
    float sf = __expf(mx - mn);
    float pe = __expf(l - mn);
    den = den * sf + pe;
    uint4 v0 = v_s[h][0][m];
    uint4 v1 = v_s[h][1][m];
    uint4 v2 = v_s[h][2][m];
    uint4 v3 = v_s[h][3][m];
    PV8(v0, 0) PV8(v1, 8) PV8(v2, 16) PV8(v3, 24)
    mx = mn;
    bcur = bnx;
  }
  float inv = 1.f / den;
  u32* op = (u32*)(ao + (size_t)(wid * 64 + n) * 256 + h * 32);
#pragma unroll
  for (int i = 0; i < 16; ++i)
    op[i] = pack2(acc[2 * i] * inv, acc[2 * i + 1] * inv);
#undef DOT8
#undef PV8
}

// ---------------- LN(ln_in)*g + b + res -> dst fp32 (+ optional bf16) -------
__global__ __launch_bounds__(256) void ln_res_kernel(
    const u16* __restrict__ ln_in, const float* __restrict__ res,
    float* __restrict__ dst, u16* __restrict__ dst_bf,
    const float* __restrict__ g, const float* __restrict__ bb, int remap) {
  int t = blockIdx.x, c = threadIdx.x;
  int p;
  if (remap) {
    int wid = t >> 6, n = t & 63;
    int b = wid >> 8, wh = (wid >> 4) & 15, ww = wid & 15;
    p = (b << 14) + ((wh * 8 + (n >> 3)) << 7) + ww * 8 + (n & 7);
  } else {
    p = t;
  }
  float v = bflo((u32)ln_in[(size_t)t * 256 + c] << 0) * 0.f;  // placeholder avoid
  v = __uint_as_float(((u32)ln_in[(size_t)t * 256 + c]) << 16);
  float s1 = v, s2 = v * v;
#pragma unroll
  for (int o = 32; o > 0; o >>= 1) {
    s1 += __shfl_down(s1, o);
    s2 += __shfl_down(s2, o);
  }
  __shared__ float red[8];
  if ((c & 63) == 0) {
    red[c >> 6] = s1;
    red[4 + (c >> 6)] = s2;
  }
  __syncthreads();
  s1 = red[0] + red[1] + red[2] + red[3];
  s2 = red[4] + red[5] + red[6] + red[7];
  float mean = s1 * (1.f / 256.f);
  float var = s2 * (1.f / 256.f) - mean * mean;
  float rs = rsqrtf(var + 1e-5f);
  float ln = (v - mean) * rs * g[c] + bb[c];
  float o = res[(size_t)p * 256 + c] + ln;
  dst[(size_t)p * 256 + c] = o;
  if (dst_bf) dst_bf[(size_t)p * 256 + c] = f2bf(o);
}

// ---------------- NHWC [P][256] fp32 -> NCHW output -------------------------
__global__ __launch_bounds__(256) void transpose_kernel(
    const float* __restrict__ F, float* __restrict__ outp) {
  __shared__ float tl[64][65];
  int bid = blockIdx.x;
  int b = bid >> 10;
  int r = bid & 1023;
  int ct = r >> 8, hwt = r & 255;
  int c0 = ct << 6, hw0 = hwt << 6;
  int tid = threadIdx.x;
  for (int e = tid; e < 4096; e += 256) {
    int p = e >> 6, cc = e & 63;
    tl[p][cc] = F[(size_t)(b * HW + hw0 + p) * 256 + c0 + cc];
  }
  __syncthreads();
  for (int e = tid; e < 4096; e += 256) {
    int cc = e >> 6, p = e & 63;
    outp[(size_t)(b * 256 + c0 + cc) * HW + hw0 + p] = tl[p][cc];
  }
}

// ---------------------------------------------------------------------------
extern "C" void kernel_launch(void* const* d_in, const int* in_sizes, int n_in,
                              void* d_out, int out_size, void* d_ws, size_t ws_size,
                              hipStream_t stream) {
  const float* x        = (const float*)d_in[0];
  const float* w_stem   = (const float*)d_in[1];
  const float* s_stem   = (const float*)d_in[2];
  const float* b_stem   = (const float*)d_in[3];
  const float* w_blk    = (const float*)d_in[4];
  const float* s_blk    = (const float*)d_in[5];
  const float* b_blk    = (const float*)d_in[6];
  const float* norm1_g  = (const float*)d_in[7];
  const float* norm1_b  = (const float*)d_in[8];
  const float* qkv_w    = (const float*)d_in[9];
  const float* qkv_b    = (const float*)d_in[10];
  const float* proj_w   = (const float*)d_in[11];
  const float* proj_b   = (const float*)d_in[12];
  const float* logit_sc = (const float*)d_in[13];
  const float* cpb_w1   = (const float*)d_in[14];
  const float* cpb_b1   = (const float*)d_in[15];
  const float* cpb_w2   = (const float*)d_in[16];
  const float* norm2_g  = (const float*)d_in[17];
  const float* norm2_b  = (const float*)d_in[18];
  const float* mlp_w1   = (const float*)d_in[19];
  const float* mlp_b1   = (const float*)d_in[20];
  const float* mlp_w2   = (const float*)d_in[21];
  const float* mlp_b2   = (const float*)d_in[22];
  float* out = (float*)d_out;
  float* ws = (float*)d_ws;
  (void)in_sizes; (void)n_in; (void)out_size; (void)ws_size;

  // ---- workspace layout (floats), total 50,726,912 (~203 MB) ----
  float* E    = ws;                        // 16,777,216 : e fp32 -> S in place
  float* R1   = ws + 16777216;             // 16,777,216
  float* R2   = ws + 33554432;             // 16,777,216
  float* WRB  = ws + 50331648;             // 147,456 conv blk w (fp32)
  float* WRS  = WRB + 147456;              // 16,384 stem w (fp32)
  float* BPRE = WRS + 16384;               // 2,048
  float* BFT  = BPRE + 2048;               // 32,768 bias_t[h][m][n]
  u16*   QWB  = (u16*)(BFT + 32768);       // 196,608 bf16 (=98,304 f)
  u16*   PWB  = (u16*)(BFT + 32768 + 98304);        // 65,536 bf16
  u16*   M1WB = (u16*)(BFT + 32768 + 98304 + 32768);
  u16*   M2WB = (u16*)(BFT + 32768 + 98304 + 65536);

  // conv-phase overlays
  float* convA  = R1;
  float* convS  = R1 + 4194304;
  float* convC1 = R1 + 8388608;
  float* convE3 = R1 + 12582912;
  float* convB  = R2;
  float* convD  = R2 + 4194304;

  // matmul-phase overlays (lifetimes verified disjoint)
  u16* EBF = (u16*)(R2 + 8388608);   // 16.78M bf16 (e)
  u16* QKV = (u16*)R1;               // 50.33M bf16 = R1 full + R2[0:8.39M f)
  u16* AO  = (u16*)(R2 + 8388608);   // 16.78M bf16 (over EBF, after it's dead)
  u16* P   = (u16*)R1;               // proj out (over QKV head)
  u16* SBF = (u16*)R2;               // S bf16 (over QKV tail)
  u16* Hb  = (u16*)R1;               // mlp hidden (over P)
  u16* H2  = (u16*)(R1 + 8388608);   // mlp out
  float* F = R2;                     // final NHWC fp32

  // ---- param prep ----
  repack_kernel<<<640, 256, 0, stream>>>(w_blk, w_stem, WRB, WRS);
  castw_kernel<<<768, 256, 0, stream>>>(qkv_w, QWB, 196608);
  castw_kernel<<<256, 256, 0, stream>>>(proj_w, PWB, 65536);
  castw_kernel<<<256, 256, 0, stream>>>(mlp_w1, M1WB, 65536);
  castw_kernel<<<256, 256, 0, stream>>>(mlp_w2, M2WB, 65536);
  cpb_mlp_kernel<<<225, 512, 0, stream>>>(cpb_w1, cpb_b1, cpb_w2, BPRE);
  cpb_expand_kernel<<<16, 256, 0, stream>>>(BPRE, BFT);

  // ---- ELAN convs (fp32) ----
  stem_kernel<<<1024, 256, 0, stream>>>(x, WRS, s_stem, b_stem, convA, convS);
  dim3 cgrid(8, 8, 4);
  conv3x3_kernel<<<cgrid, 256, 0, stream>>>(convA, convB, WRB, s_blk, b_blk);
  conv3x3_kernel<<<cgrid, 256, 0, stream>>>(convB, convC1, WRB + 36864, s_blk + 64, b_blk + 64);
  conv3x3_kernel<<<cgrid, 256, 0, stream>>>(convC1, convD, WRB + 73728, s_blk + 128, b_blk + 128);
  conv3x3_kernel<<<cgrid, 256, 0, stream>>>(convD, convE3, WRB + 110592, s_blk + 192, b_blk + 192);
  pack_kernel<<<4096, 256, 0, stream>>>(convE3, convC1, convA, convS, E, EBF);

  // ---- qkv GEMM (bf16 MFMA) ----
  dim3 gq(512, 12);
  gemm_bf16_kernel<<<gq, 256, 0, stream>>>(EBF, QWB, qkv_b, QKV, 768, 0);

  // ---- window attention ----
  attn_kernel<<<1024, 512, 0, stream>>>(QKV, logit_sc, BFT, AO);

  // ---- proj + LN1 + MLP + LN2 ----
  dim3 g4(512, 4);
  gemm_bf16_kernel<<<g4, 256, 0, stream>>>(AO, PWB, proj_b, P, 256, 0);
  ln_res_kernel<<<65536, 256, 0, stream>>>(P, E, E, SBF, norm1_g, norm1_b, 1);
  gemm_bf16_kernel<<<g4, 256, 0, stream>>>(SBF, M1WB, mlp_b1, Hb, 256, 1);
  gemm_bf16_kernel<<<g4, 256, 0, stream>>>(Hb, M2WB, mlp_b2, H2, 256, 0);
  ln_res_kernel<<<65536, 256, 0, stream>>>(H2, E, F, (u16*)nullptr, norm2_g, norm2_b, 0);
  transpose_kernel<<<4096, 256, 0, stream>>>(F, out);
}

// Round 3
// 614.166 us; speedup vs baseline: 3.9318x; 2.0989x over previous
//
#include <hip/hip_runtime.h>
#include <hip/hip_bf16.h>
#include <math.h>

// ---------------------------------------------------------------------------
// ELAN + SwinV2: bf16 MFMA convs (implicit GEMM) + bf16 MFMA GEMMs + fused attn.
// B=4, C_IN=128, H=W=128, DIM=256, WS=8, HEADS=8, HEAD_DIM=32.
// ---------------------------------------------------------------------------

#define HW 16384
typedef unsigned int u32;
typedef unsigned short u16;
typedef __attribute__((ext_vector_type(8))) short short8;   // bf16x8 MFMA frag
typedef __attribute__((ext_vector_type(4))) float floatx4;  // f32x4 acc frag

__device__ __forceinline__ float silu_f(float y) { return y / (1.f + expf(-y)); }
__device__ __forceinline__ float bflo(u32 u) { return __uint_as_float(u << 16); }
__device__ __forceinline__ float bfhi(u32 u) { return __uint_as_float(u & 0xffff0000u); }
__device__ __forceinline__ float bf2f(u16 v) { return __uint_as_float((u32)v << 16); }
__device__ __forceinline__ u16 f2bf(float x) {
  u32 u = __float_as_uint(x);
  u += 0x7fffu + ((u >> 16) & 1u);
  return (u16)(u >> 16);
}
__device__ __forceinline__ u32 pack2(float a, float b) {
  return (u32)f2bf(a) | ((u32)f2bf(b) << 16);
}

#define GLDS16(gp, lp)                                           \
  __builtin_amdgcn_global_load_lds(                              \
      (const __attribute__((address_space(1))) void*)(gp),       \
      (__attribute__((address_space(3))) void*)(lp), 16, 0, 0)

// ---------------- weight repack: conv weights -> bf16, BN scale folded ------
__global__ __launch_bounds__(256) void repack_kernel(
    const float* __restrict__ w_blk, const float* __restrict__ s_blk,
    const float* __restrict__ w_stem, const float* __restrict__ s_stem,
    u16* __restrict__ wtc, u16* __restrict__ wts) {
  int idx = blockIdx.x * 256 + threadIdx.x;
  if (idx < 147456) {
    // wtc[((conv*9+t)*64+oc)*64 + c]
    int c = idx & 63;
    int rest = idx >> 6;
    int oc = rest & 63;
    int ct = rest >> 6;
    int conv = ct / 9, t = ct % 9;
    float w = w_blk[((size_t)(conv * 64 + oc) * 64 + c) * 9 + t];
    wtc[idx] = f2bf(w * s_blk[conv * 64 + oc]);
  } else if (idx < 147456 + 16384) {
    int j = idx - 147456;  // oc*128 + c ; oc in [0,128): 0-63 main, 64-127 short
    int c = j & 127, oc = j >> 7;
    float w = w_stem[(size_t)oc * 128 + c];
    wts[j] = f2bf(w * s_stem[oc]);
  }
}

// ---------------- generic fp32 -> bf16 cast (weights) ----------------------
__global__ __launch_bounds__(256) void castw_kernel(
    const float* __restrict__ in, u16* __restrict__ outp, int n) {
  int i = blockIdx.x * 256 + threadIdx.x;
  if (i < n) outp[i] = f2bf(in[i]);
}

// ---------------- continuous position bias MLP -----------------------------
__global__ __launch_bounds__(512) void cpb_mlp_kernel(
    const float* __restrict__ w1, const float* __restrict__ b1,
    const float* __restrict__ w2, float* __restrict__ pre) {
  __shared__ float hb[512];
  int t = blockIdx.x, j = threadIdx.x;
  int i = t / 15, jj = t % 15;
  float c0 = (float)(i - 7) * (8.f / 7.f);
  float c1 = (float)(jj - 7) * (8.f / 7.f);
  float s0 = (c0 > 0.f) ? 1.f : ((c0 < 0.f) ? -1.f : 0.f);
  float s1 = (c1 > 0.f) ? 1.f : ((c1 < 0.f) ? -1.f : 0.f);
  float t0 = s0 * log2f(fabsf(c0) + 1.f) * (1.f / 3.f);
  float t1 = s1 * log2f(fabsf(c1) + 1.f) * (1.f / 3.f);
  float h = t0 * w1[j * 2] + t1 * w1[j * 2 + 1] + b1[j];
  hb[j] = fmaxf(h, 0.f);
  __syncthreads();
  if (j < 8) {
    float s = 0.f;
    for (int k = 0; k < 512; ++k) s += hb[k] * w2[j * 512 + k];
    pre[t * 8 + j] = s;
  }
}

// bias_t[h][m][n] (key-major so attn's per-m load is lane-coalesced over n)
__global__ __launch_bounds__(256) void cpb_expand_kernel(
    const float* __restrict__ pre, float* __restrict__ bias_t) {
  int idx = blockIdx.x * 256 + threadIdx.x;  // 4096 (m,n) pairs
  int m = idx >> 6, n = idx & 63;
  int di = (n >> 3) - (m >> 3) + 7;
  int dj = (n & 7) - (m & 7) + 7;
  int ti = di * 15 + dj;
#pragma unroll
  for (int h = 0; h < 8; ++h) {
    float v = pre[ti * 8 + h];
    bias_t[h * 4096 + idx] = 16.f / (1.f + expf(-v));
  }
}

// ---------------- x NCHW fp32 -> XT NHWC bf16 -------------------------------
__global__ __launch_bounds__(256) void transpose_in_kernel(
    const float* __restrict__ x, u16* __restrict__ xt) {
  __shared__ float tl[64][65];
  int bid = blockIdx.x;  // 2048 = 4 b * 2 cs * 256 hws
  int b = bid >> 9;
  int r = bid & 511;
  int cs = r >> 8, hws = r & 255;
  int c0 = cs << 6, hw0 = hws << 6;
  int tid = threadIdx.x;
  for (int e = tid; e < 4096; e += 256) {
    int c = e >> 6, p = e & 63;
    tl[c][p] = x[(size_t)(b * 128 + c0 + c) * HW + hw0 + p];
  }
  __syncthreads();
  for (int e = tid; e < 4096; e += 256) {
    int p = e >> 6, c = e & 63;
    xt[(size_t)(b * HW + hw0 + p) * 128 + c0 + c] = f2bf(tl[c][p]);
  }
}

// ---------------- bf16 MFMA GEMM: C[.,col]=act(A[M,K] @ W[N,K]^T + b) -------
// Tile 128x64, BK=64, XOR-swizzled LDS. C stride ldc (u16 elements).
__global__ __launch_bounds__(256, 4) void gemm_bf16_kernel(
    const u16* __restrict__ A, const u16* __restrict__ W,
    const float* __restrict__ bias, u16* __restrict__ C, int K, int ldc,
    int act) {
  __shared__ u16 As[128 * 64];
  __shared__ u16 Ws[64 * 64];
  int tid = threadIdx.x;
  int wv = tid >> 6, lane = tid & 63;
  int m0 = blockIdx.x * 128, n0 = blockIdx.y * 64;
  floatx4 zz = {0.f, 0.f, 0.f, 0.f};
  floatx4 acc[2][4];
#pragma unroll
  for (int i = 0; i < 2; ++i)
#pragma unroll
    for (int j = 0; j < 4; ++j) acc[i][j] = zz;
  int lr = lane >> 3, ls = lane & 7;
  for (int k0 = 0; k0 < K; k0 += 64) {
#pragma unroll
    for (int i = 0; i < 4; ++i) {
      int ci = wv * 4 + i;
      int r = ci * 8 + lr;
      int cc = ls ^ (r & 7);
      GLDS16(A + (size_t)(m0 + r) * K + k0 + cc * 8, As + ci * 512);
    }
#pragma unroll
    for (int i = 0; i < 2; ++i) {
      int ci = wv * 2 + i;
      int r = ci * 8 + lr;
      int cc = ls ^ (r & 7);
      GLDS16(W + (size_t)(n0 + r) * K + k0 + cc * 8, Ws + ci * 512);
    }
    __syncthreads();
#pragma unroll
    for (int kk = 0; kk < 2; ++kk) {
      int g = kk * 4 + (lane >> 4);
      short8 a0, a1, b0, b1, b2, b3;
      {
        int row = wv * 32 + (lane & 15);
        a0 = *(const short8*)&As[row * 64 + (g ^ (row & 7)) * 8];
        int row2 = row + 16;
        a1 = *(const short8*)&As[row2 * 64 + (g ^ (row2 & 7)) * 8];
      }
      {
        int col = lane & 15;
        b0 = *(const short8*)&Ws[col * 64 + (g ^ (col & 7)) * 8];
        int c1 = col + 16;
        b1 = *(const short8*)&Ws[c1 * 64 + (g ^ (c1 & 7)) * 8];
        int c2 = col + 32;
        b2 = *(const short8*)&Ws[c2 * 64 + (g ^ (c2 & 7)) * 8];
        int c3 = col + 48;
        b3 = *(const short8*)&Ws[c3 * 64 + (g ^ (c3 & 7)) * 8];
      }
      acc[0][0] = __builtin_amdgcn_mfma_f32_16x16x32_bf16(a0, b0, acc[0][0], 0, 0, 0);
      acc[0][1] = __builtin_amdgcn_mfma_f32_16x16x32_bf16(a0, b1, acc[0][1], 0, 0, 0);
      acc[0][2] = __builtin_amdgcn_mfma_f32_16x16x32_bf16(a0, b2, acc[0][2], 0, 0, 0);
      acc[0][3] = __builtin_amdgcn_mfma_f32_16x16x32_bf16(a0, b3, acc[0][3], 0, 0, 0);
      acc[1][0] = __builtin_amdgcn_mfma_f32_16x16x32_bf16(a1, b0, acc[1][0], 0, 0, 0);
      acc[1][1] = __builtin_amdgcn_mfma_f32_16x16x32_bf16(a1, b1, acc[1][1], 0, 0, 0);
      acc[1][2] = __builtin_amdgcn_mfma_f32_16x16x32_bf16(a1, b2, acc[1][2], 0, 0, 0);
      acc[1][3] = __builtin_amdgcn_mfma_f32_16x16x32_bf16(a1, b3, acc[1][3], 0, 0, 0);
    }
    __syncthreads();
  }
  int rbase = wv * 32 + ((lane >> 4) << 2);
  int cb = lane & 15;
#pragma unroll
  for (int mi = 0; mi < 2; ++mi) {
#pragma unroll
    for (int nj = 0; nj < 4; ++nj) {
      int col = n0 + nj * 16 + cb;
      float bv = bias[col];
#pragma unroll
      for (int r = 0; r < 4; ++r) {
        int row = m0 + rbase + mi * 16 + r;
        float v = acc[mi][nj][r] + bv;
        if (act == 1) v = 0.5f * v * (1.f + erff(v * 0.70710678118654752f));
        else if (act == 2) v = silu_f(v);
        C[(size_t)row * ldc + col] = f2bf(v);
      }
    }
  }
}

// ---------------- 3x3 conv 64->64 pad1 SiLU, NHWC bf16, implicit MFMA GEMM --
// A = weights (oc rows), B = pixels (cols). Block: 8x8 pixels, 4 waves.
// in: pixel stride istr; out: pixel stride ostr. wt[9][64][64], bias fp32[64].
__global__ __launch_bounds__(256) void conv3x3_mfma_kernel(
    const u16* __restrict__ in, int istr, u16* __restrict__ outp, int ostr,
    const u16* __restrict__ wt, const float* __restrict__ bias) {
  __shared__ u16 tile[6400];  // [100 pixels][64 c], 16B-chunk XOR swizzle
  int tid = threadIdx.x;
  int wv = tid >> 6, lane = tid & 63;
  int bx = blockIdx.x, by = blockIdx.y, b = blockIdx.z;
  int h0 = by * 8, w0 = bx * 8;
  // ---- stage halo 10x10x64 (800 16B-slots over 4 rounds) ----
#pragma unroll
  for (int rr = 0; rr < 4; ++rr) {
    int slot = rr * 256 + tid;
    int p = slot >> 3, ch = slot & 7;
    if (p < 100) {
      int hr = p / 10, hc = p % 10;
      int gh = h0 + hr - 1, gw = w0 + hc - 1;
      bool ok = (gh >= 0) && (gh < 128) && (gw >= 0) && (gw < 128);
      uint4 v = {0u, 0u, 0u, 0u};
      if (ok) {
        size_t pix = (size_t)((b * 128 + gh) * 128 + gw);
        v = *(const uint4*)(in + pix * istr + ch * 8);
      }
      *(uint4*)(tile + p * 64 + ((ch ^ (p & 7)) << 3)) = v;
    }
  }
  __syncthreads();
  int pl = lane & 15;   // A: oc row-in-frag ; B/C: pixel col-in-group
  int g = lane >> 4;    // k sub-slice
  int prow = 2 * wv + (pl >> 3), pcol = pl & 7;  // output pixel (rel tile)
  floatx4 zz = {0.f, 0.f, 0.f, 0.f};
  floatx4 acc[4] = {zz, zz, zz, zz};
#pragma unroll
  for (int t = 0; t < 9; ++t) {
    int dy = t / 3, dx = t % 3;
    int hp = (prow + dy) * 10 + (pcol + dx);
    short8 bf0 = *(const short8*)&tile[hp * 64 + (((0 * 4 + g) ^ (hp & 7)) << 3)];
    short8 bf1 = *(const short8*)&tile[hp * 64 + (((1 * 4 + g) ^ (hp & 7)) << 3)];
    const u16* wtap = wt + t * 4096;
#pragma unroll
    for (int nf = 0; nf < 4; ++nf) {
      short8 a0 = *(const short8*)&wtap[(nf * 16 + pl) * 64 + g * 8];
      short8 a1 = *(const short8*)&wtap[(nf * 16 + pl) * 64 + 32 + g * 8];
      acc[nf] = __builtin_amdgcn_mfma_f32_16x16x32_bf16(a0, bf0, acc[nf], 0, 0, 0);
      acc[nf] = __builtin_amdgcn_mfma_f32_16x16x32_bf16(a1, bf1, acc[nf], 0, 0, 0);
    }
  }
  // ---- epilogue: oc = nf*16 + g*4 + r (A side), pixel = pl (B side) ----
  size_t pix = (size_t)((b * 128 + h0 + prow) * 128 + w0 + pcol);
#pragma unroll
  for (int nf = 0; nf < 4; ++nf) {
    float o0 = silu_f(acc[nf][0] + bias[nf * 16 + g * 4 + 0]);
    float o1 = silu_f(acc[nf][1] + bias[nf * 16 + g * 4 + 1]);
    float o2 = silu_f(acc[nf][2] + bias[nf * 16 + g * 4 + 2]);
    float o3 = silu_f(acc[nf][3] + bias[nf * 16 + g * 4 + 3]);
    uint2 w2;
    w2.x = pack2(o0, o1);
    w2.y = pack2(o2, o3);
    *(uint2*)(outp + pix * ostr + nf * 16 + g * 4) = w2;
  }
}

// ---------------- window attention: block = window, wave = head --------------
__global__ __launch_bounds__(512, 4) void attn_kernel(
    const u16* __restrict__ qkv, const float* __restrict__ logit_scale,
    const float* __restrict__ bias_t, u16* __restrict__ ao) {
  __shared__ uint4 kn_s[8][4][64];  // [head][slot(8 bf16)][token]
  __shared__ uint4 v_s[8][4][64];
  int tid = threadIdx.x;
  int h = __builtin_amdgcn_readfirstlane(tid >> 6);
  int n = tid & 63;
  int wid = blockIdx.x;
  int b = wid >> 8, wh = (wid >> 4) & 15, ww = wid & 15;
  int p = (b << 14) + ((wh * 8 + (n >> 3)) << 7) + ww * 8 + (n & 7);
  const u32* qp = (const u32*)(qkv + (size_t)p * 768 + h * 32);

  float scale = __expf(fminf(logit_scale[h], 4.6051701860f));
  float qf[32];
#pragma unroll
  for (int i = 0; i < 16; ++i) {
    u32 u = qp[i];
    qf[2 * i] = bflo(u);
    qf[2 * i + 1] = bfhi(u);
  }
  float sq = 0.f;
#pragma unroll
  for (int d = 0; d < 32; ++d) sq += qf[d] * qf[d];
  float rq = scale / fmaxf(sqrtf(sq), 1e-12f);
#pragma unroll
  for (int d = 0; d < 32; ++d) qf[d] *= rq;

  {  // K: load, normalize, stage
    float kf[32];
#pragma unroll
    for (int i = 0; i < 16; ++i) {
      u32 u = qp[128 + i];
      kf[2 * i] = bflo(u);
      kf[2 * i + 1] = bfhi(u);
    }
    float sk = 0.f;
#pragma unroll
    for (int d = 0; d < 32; ++d) sk += kf[d] * kf[d];
    float rk = 1.f / fmaxf(sqrtf(sk), 1e-12f);
#pragma unroll
    for (int sl = 0; sl < 4; ++sl) {
      uint4 w4;
      w4.x = pack2(kf[sl * 8 + 0] * rk, kf[sl * 8 + 1] * rk);
      w4.y = pack2(kf[sl * 8 + 2] * rk, kf[sl * 8 + 3] * rk);
      w4.z = pack2(kf[sl * 8 + 4] * rk, kf[sl * 8 + 5] * rk);
      w4.w = pack2(kf[sl * 8 + 6] * rk, kf[sl * 8 + 7] * rk);
      kn_s[h][sl][n] = w4;
    }
  }
  {  // V: stage as-is
#pragma unroll
    for (int sl = 0; sl < 4; ++sl) {
      uint4 w4;
      w4.x = qp[256 + sl * 4 + 0];
      w4.y = qp[256 + sl * 4 + 1];
      w4.z = qp[256 + sl * 4 + 2];
      w4.w = qp[256 + sl * 4 + 3];
      v_s[h][sl][n] = w4;
    }
  }
  __syncthreads();

  const float* brow = bias_t + h * 4096 + n;
  float bcur = brow[0];
  float mx = -3.4e38f, den = 0.f;
  float acc[32];
#pragma unroll
  for (int d = 0; d < 32; ++d) acc[d] = 0.f;

#define DOT8(uu, base)                                             \
  s += bflo(uu.x) * qf[base + 0] + bfhi(uu.x) * qf[base + 1] +     \
       bflo(uu.y) * qf[base + 2] + bfhi(uu.y) * qf[base + 3] +     \
       bflo(uu.z) * qf[base + 4] + bfhi(uu.z) * qf[base + 5] +     \
       bflo(uu.w) * qf[base + 6] + bfhi(uu.w) * qf[base + 7];
#define PV8(vv, base)                                              \
  acc[base + 0] = acc[base + 0] * sf + pe * bflo(vv.x);            \
  acc[base + 1] = acc[base + 1] * sf + pe * bfhi(vv.x);            \
  acc[base + 2] = acc[base + 2] * sf + pe * bflo(vv.y);            \
  acc[base + 3] = acc[base + 3] * sf + pe * bfhi(vv.y);            \
  acc[base + 4] = acc[base + 4] * sf + pe * bflo(vv.z);            \
  acc[base + 5] = acc[base + 5] * sf + pe * bfhi(vv.z);            \
  acc[base + 6] = acc[base + 6] * sf + pe * bflo(vv.w);            \
  acc[base + 7] = acc[base + 7] * sf + pe * bfhi(vv.w);

  for (int m = 0; m < 64; ++m) {
    float bnx = (m < 63) ? brow[(m + 1) * 64] : 0.f;
    uint4 k0 = kn_s[h][0][m];
    uint4 k1 = kn_s[h][1][m];
    uint4 k2 = kn_s[h][2][m];
    uint4 k3 = kn_s[h][3][m];
    float s = 0.f;
    DOT8(k0, 0) DOT8(k1, 8) DOT8(k2, 16) DOT8(k3, 24)
    float l = s + bcur;
    float mn = fmaxf(mx, l);
    float sf = __expf(mx - mn);
    float pe = __expf(l - mn);
    den = den * sf + pe;
    uint4 v0 = v_s[h][0][m];
    uint4 v1 = v_s[h][1][m];
    uint4 v2 = v_s[h][2][m];
    uint4 v3 = v_s[h][3][m];
    PV8(v0, 0) PV8(v1, 8) PV8(v2, 16) PV8(v3, 24)
    mx = mn;
    bcur = bnx;
  }
  float inv = 1.f / den;
  u32* op = (u32*)(ao + (size_t)(wid * 64 + n) * 256 + h * 32);
#pragma unroll
  for (int i = 0; i < 16; ++i)
    op[i] = pack2(acc[2 * i] * inv, acc[2 * i + 1] * inv);
#undef DOT8
#undef PV8
}

// ---------------- LN(ln_in)*g + b + res -> dst fp32 (+ optional bf16) -------
// res from fp32 ptr (res_f) or bf16 ptr (res_b). remap=1: ln_in token-major.
__global__ __launch_bounds__(256) void ln_res_kernel(
    const u16* __restrict__ ln_in, const float* __restrict__ res_f,
    const u16* __restrict__ res_b, float* __restrict__ dst,
    u16* __restrict__ dst_bf, const float* __restrict__ g,
    const float* __restrict__ bb, int remap) {
  int t = blockIdx.x, c = threadIdx.x;
  int p;
  if (remap) {
    int wid = t >> 6, n = t & 63;
    int b = wid >> 8, wh = (wid >> 4) & 15, ww = wid & 15;
    p = (b << 14) + ((wh * 8 + (n >> 3)) << 7) + ww * 8 + (n & 7);
  } else {
    p = t;
  }
  float v = bf2f(ln_in[(size_t)t * 256 + c]);
  float s1 = v, s2 = v * v;
#pragma unroll
  for (int o = 32; o > 0; o >>= 1) {
    s1 += __shfl_down(s1, o);
    s2 += __shfl_down(s2, o);
  }
  __shared__ float red[8];
  if ((c & 63) == 0) {
    red[c >> 6] = s1;
    red[4 + (c >> 6)] = s2;
  }
  __syncthreads();
  s1 = red[0] + red[1] + red[2] + red[3];
  s2 = red[4] + red[5] + red[6] + red[7];
  float mean = s1 * (1.f / 256.f);
  float var = s2 * (1.f / 256.f) - mean * mean;
  float rs = rsqrtf(var + 1e-5f);
  float ln = (v - mean) * rs * g[c] + bb[c];
  float r = res_f ? res_f[(size_t)p * 256 + c] : bf2f(res_b[(size_t)p * 256 + c]);
  float o = r + ln;
  dst[(size_t)p * 256 + c] = o;
  if (dst_bf) dst_bf[(size_t)p * 256 + c] = f2bf(o);
}

// ---------------- NHWC [P][256] fp32 -> NCHW output -------------------------
__global__ __launch_bounds__(256) void transpose_kernel(
    const float* __restrict__ F, float* __restrict__ outp) {
  __shared__ float tl[64][65];
  int bid = blockIdx.x;
  int b = bid >> 10;
  int r = bid & 1023;
  int ct = r >> 8, hwt = r & 255;
  int c0 = ct << 6, hw0 = hwt << 6;
  int tid = threadIdx.x;
  for (int e = tid; e < 4096; e += 256) {
    int p = e >> 6, cc = e & 63;
    tl[p][cc] = F[(size_t)(b * HW + hw0 + p) * 256 + c0 + cc];
  }
  __syncthreads();
  for (int e = tid; e < 4096; e += 256) {
    int cc = e >> 6, p = e & 63;
    outp[(size_t)(b * 256 + c0 + cc) * HW + hw0 + p] = tl[p][cc];
  }
}

// ---------------------------------------------------------------------------
extern "C" void kernel_launch(void* const* d_in, const int* in_sizes, int n_in,
                              void* d_out, int out_size, void* d_ws, size_t ws_size,
                              hipStream_t stream) {
  const float* x        = (const float*)d_in[0];
  const float* w_stem   = (const float*)d_in[1];
  const float* s_stem   = (const float*)d_in[2];
  const float* b_stem   = (const float*)d_in[3];
  const float* w_blk    = (const float*)d_in[4];
  const float* s_blk    = (const float*)d_in[5];
  const float* b_blk    = (const float*)d_in[6];
  const float* norm1_g  = (const float*)d_in[7];
  const float* norm1_b  = (const float*)d_in[8];
  const float* qkv_w    = (const float*)d_in[9];
  const float* qkv_b    = (const float*)d_in[10];
  const float* proj_w   = (const float*)d_in[11];
  const float* proj_b   = (const float*)d_in[12];
  const float* logit_sc = (const float*)d_in[13];
  const float* cpb_w1   = (const float*)d_in[14];
  const float* cpb_b1   = (const float*)d_in[15];
  const float* cpb_w2   = (const float*)d_in[16];
  const float* norm2_g  = (const float*)d_in[17];
  const float* norm2_b  = (const float*)d_in[18];
  const float* mlp_w1   = (const float*)d_in[19];
  const float* mlp_b1   = (const float*)d_in[20];
  const float* mlp_w2   = (const float*)d_in[21];
  const float* mlp_b2   = (const float*)d_in[22];
  float* out = (float*)d_out;
  float* ws = (float*)d_ws;
  (void)in_sizes; (void)n_in; (void)out_size; (void)ws_size;

  // ---- workspace regions (floats) ----
  float* R0 = ws;                  // 16,777,216
  float* R1 = ws + 16777216;       // 16,777,216
  float* R2 = ws + 33554432;       // 16,777,216
  float* TAIL = ws + 50331648;
  u16* WTC  = (u16*)TAIL;                    // 147,456 u16 (73,728 f)
  u16* WTS  = (u16*)(TAIL + 73728);          // 16,384 u16 (8,192 f)
  u16* QWB  = (u16*)(TAIL + 81920);          // 196,608 u16 (98,304 f)
  u16* PWB  = (u16*)(TAIL + 180224);         // 65,536 u16 (32,768 f)
  u16* M1WB = (u16*)(TAIL + 212992);
  u16* M2WB = (u16*)(TAIL + 245760);
  float* BPRE = TAIL + 278528;               // 2,048 f
  float* BFT  = TAIL + 280576;               // 32,768 f

  // phase overlays (lifetimes verified disjoint):
  u16* XT  = (u16*)R2;               // [65536][128] bf16, dead after stem gemm
  u16* EBF = (u16*)(R2 + 8388608);   // [65536][256] bf16 NHWC e; lives to ln1
  u16* T1  = (u16*)R1;               // conv intermediate [65536][64]
  u16* T2  = (u16*)(R1 + 2097152);
  u16* QKV = (u16*)R1;               // [65536][768] = R1 full + R2[0:8.39M f)
  u16* AO  = (u16*)R0;               // attn out [65536][256]
  u16* P   = (u16*)(R0 + 8388608);   // proj out
  float* S = R1;                     // post-LN1 residual fp32 (after attn)
  u16* SBF = (u16*)R0;               // S bf16 (over AO)
  u16* Hb  = (u16*)R2;               // mlp hidden (over QKV tail)
  u16* H2  = (u16*)(R0 + 8388608);   // mlp out (over P)
  float* F = R2;                     // final NHWC fp32 (over Hb+EBF)

  // ---- param prep ----
  repack_kernel<<<640, 256, 0, stream>>>(w_blk, s_blk, w_stem, s_stem, WTC, WTS);
  castw_kernel<<<768, 256, 0, stream>>>(qkv_w, QWB, 196608);
  castw_kernel<<<256, 256, 0, stream>>>(proj_w, PWB, 65536);
  castw_kernel<<<256, 256, 0, stream>>>(mlp_w1, M1WB, 65536);
  castw_kernel<<<256, 256, 0, stream>>>(mlp_w2, M2WB, 65536);
  cpb_mlp_kernel<<<225, 512, 0, stream>>>(cpb_w1, cpb_b1, cpb_w2, BPRE);
  cpb_expand_kernel<<<16, 256, 0, stream>>>(BPRE, BFT);

  // ---- input transpose + stem (1x1 conv = GEMM, SiLU) -> EBF ch 128..255 ----
  transpose_in_kernel<<<2048, 256, 0, stream>>>(x, XT);
  dim3 gs(512, 2);
  gemm_bf16_kernel<<<gs, 256, 0, stream>>>(XT, WTS, b_stem, EBF + 128, 128, 256, 2);

  // ---- ELAN 3x3 convs (bf16 MFMA implicit GEMM) ----
  dim3 cgrid(16, 16, 4);
  conv3x3_mfma_kernel<<<cgrid, 256, 0, stream>>>(EBF + 128, 256, T1, 64, WTC, b_blk);
  conv3x3_mfma_kernel<<<cgrid, 256, 0, stream>>>(T1, 64, EBF + 64, 256, WTC + 9 * 4096, b_blk + 64);
  conv3x3_mfma_kernel<<<cgrid, 256, 0, stream>>>(EBF + 64, 256, T2, 64, WTC + 18 * 4096, b_blk + 128);
  conv3x3_mfma_kernel<<<cgrid, 256, 0, stream>>>(T2, 64, EBF, 256, WTC + 27 * 4096, b_blk + 192);

  // ---- qkv GEMM (bf16 MFMA) ----
  dim3 gq(512, 12);
  gemm_bf16_kernel<<<gq, 256, 0, stream>>>(EBF, QWB, qkv_b, QKV, 256, 768, 0);

  // ---- window attention ----
  attn_kernel<<<1024, 512, 0, stream>>>(QKV, logit_sc, BFT, AO);

  // ---- proj + LN1 + MLP + LN2 ----
  dim3 g4(512, 4);
  gemm_bf16_kernel<<<g4, 256, 0, stream>>>(AO, PWB, proj_b, P, 256, 256, 0);
  ln_res_kernel<<<65536, 256, 0, stream>>>(P, nullptr, EBF, S, SBF, norm1_g, norm1_b, 1);
  gemm_bf16_kernel<<<g4, 256, 0, stream>>>(SBF, M1WB, mlp_b1, Hb, 256, 256, 1);
  gemm_bf16_kernel<<<g4, 256, 0, stream>>>(Hb, M2WB, mlp_b2, H2, 256, 256, 0);
  ln_res_kernel<<<65536, 256, 0, stream>>>(H2, S, nullptr, F, (u16*)nullptr, norm2_g, norm2_b, 0);
  transpose_kernel<<<4096, 256, 0, stream>>>(F, out);
}

// Round 4
// 464.346 us; speedup vs baseline: 5.2004x; 1.3226x over previous
//
#include <hip/hip_runtime.h>
#include <hip/hip_bf16.h>
#include <math.h>

// ---------------------------------------------------------------------------
// ELAN + SwinV2: bf16 MFMA convs + GEMMs + MFMA window attention.
// B=4, C_IN=128, H=W=128, DIM=256, WS=8, HEADS=8, HEAD_DIM=32.
// ---------------------------------------------------------------------------

#define HW 16384
typedef unsigned int u32;
typedef unsigned short u16;
typedef __attribute__((ext_vector_type(8))) short short8;   // bf16x8 MFMA frag
typedef __attribute__((ext_vector_type(4))) float floatx4;  // f32x4 acc frag

__device__ __forceinline__ float silu_f(float y) { return y / (1.f + expf(-y)); }
__device__ __forceinline__ float bflo(u32 u) { return __uint_as_float(u << 16); }
__device__ __forceinline__ float bfhi(u32 u) { return __uint_as_float(u & 0xffff0000u); }
__device__ __forceinline__ float bf2f(u16 v) { return __uint_as_float((u32)v << 16); }
__device__ __forceinline__ u16 f2bf(float x) {
  u32 u = __float_as_uint(x);
  u += 0x7fffu + ((u >> 16) & 1u);
  return (u16)(u >> 16);
}
__device__ __forceinline__ u32 pack2(float a, float b) {
  return (u32)f2bf(a) | ((u32)f2bf(b) << 16);
}

#define GLDS16(gp, lp)                                           \
  __builtin_amdgcn_global_load_lds(                              \
      (const __attribute__((address_space(1))) void*)(gp),       \
      (__attribute__((address_space(3))) void*)(lp), 16, 0, 0)

// ---------------- weight repack: conv weights -> bf16, BN scale folded ------
__global__ __launch_bounds__(256) void repack_kernel(
    const float* __restrict__ w_blk, const float* __restrict__ s_blk,
    const float* __restrict__ w_stem, const float* __restrict__ s_stem,
    u16* __restrict__ wtc, u16* __restrict__ wts) {
  int idx = blockIdx.x * 256 + threadIdx.x;
  if (idx < 147456) {
    // wtc[((conv*9+t)*64+oc)*64 + c]
    int c = idx & 63;
    int rest = idx >> 6;
    int oc = rest & 63;
    int ct = rest >> 6;
    int conv = ct / 9, t = ct % 9;
    float w = w_blk[((size_t)(conv * 64 + oc) * 64 + c) * 9 + t];
    wtc[idx] = f2bf(w * s_blk[conv * 64 + oc]);
  } else if (idx < 147456 + 16384) {
    int j = idx - 147456;  // oc*128 + c ; oc in [0,128): 0-63 main, 64-127 short
    int c = j & 127, oc = j >> 7;
    float w = w_stem[(size_t)oc * 128 + c];
    wts[j] = f2bf(w * s_stem[oc]);
  }
}

// ---------------- generic fp32 -> bf16 cast (weights) ----------------------
__global__ __launch_bounds__(256) void castw_kernel(
    const float* __restrict__ in, u16* __restrict__ outp, int n) {
  int i = blockIdx.x * 256 + threadIdx.x;
  if (i < n) outp[i] = f2bf(in[i]);
}

// ---------------- continuous position bias MLP -----------------------------
__global__ __launch_bounds__(512) void cpb_mlp_kernel(
    const float* __restrict__ w1, const float* __restrict__ b1,
    const float* __restrict__ w2, float* __restrict__ pre) {
  __shared__ float hb[512];
  int t = blockIdx.x, j = threadIdx.x;
  int i = t / 15, jj = t % 15;
  float c0 = (float)(i - 7) * (8.f / 7.f);
  float c1 = (float)(jj - 7) * (8.f / 7.f);
  float s0 = (c0 > 0.f) ? 1.f : ((c0 < 0.f) ? -1.f : 0.f);
  float s1 = (c1 > 0.f) ? 1.f : ((c1 < 0.f) ? -1.f : 0.f);
  float t0 = s0 * log2f(fabsf(c0) + 1.f) * (1.f / 3.f);
  float t1 = s1 * log2f(fabsf(c1) + 1.f) * (1.f / 3.f);
  float h = t0 * w1[j * 2] + t1 * w1[j * 2 + 1] + b1[j];
  hb[j] = fmaxf(h, 0.f);
  __syncthreads();
  if (j < 8) {
    float s = 0.f;
    for (int k = 0; k < 512; ++k) s += hb[k] * w2[j * 512 + k];
    pre[t * 8 + j] = s;
  }
}

// bias_t[h][m][n]: bias for (key m, query n) — same indexing as verified R2/R3.
__global__ __launch_bounds__(256) void cpb_expand_kernel(
    const float* __restrict__ pre, float* __restrict__ bias_t) {
  int idx = blockIdx.x * 256 + threadIdx.x;  // 4096 (m,n) pairs
  int m = idx >> 6, n = idx & 63;
  int di = (n >> 3) - (m >> 3) + 7;
  int dj = (n & 7) - (m & 7) + 7;
  int ti = di * 15 + dj;
#pragma unroll
  for (int h = 0; h < 8; ++h) {
    float v = pre[ti * 8 + h];
    bias_t[h * 4096 + idx] = 16.f / (1.f + expf(-v));
  }
}

// ---------------- x NCHW fp32 -> XT NHWC bf16 -------------------------------
__global__ __launch_bounds__(256) void transpose_in_kernel(
    const float* __restrict__ x, u16* __restrict__ xt) {
  __shared__ float tl[64][65];
  int bid = blockIdx.x;  // 2048 = 4 b * 2 cs * 256 hws
  int b = bid >> 9;
  int r = bid & 511;
  int cs = r >> 8, hws = r & 255;
  int c0 = cs << 6, hw0 = hws << 6;
  int tid = threadIdx.x;
  for (int e = tid; e < 4096; e += 256) {
    int c = e >> 6, p = e & 63;
    tl[c][p] = x[(size_t)(b * 128 + c0 + c) * HW + hw0 + p];
  }
  __syncthreads();
  for (int e = tid; e < 4096; e += 256) {
    int p = e >> 6, c = e & 63;
    xt[(size_t)(b * HW + hw0 + p) * 128 + c0 + c] = f2bf(tl[c][p]);
  }
}

// ---------------- bf16 MFMA GEMM: C[.,col]=act(A[M,K] @ W[N,K]^T + b) -------
__global__ __launch_bounds__(256, 4) void gemm_bf16_kernel(
    const u16* __restrict__ A, const u16* __restrict__ W,
    const float* __restrict__ bias, u16* __restrict__ C, int K, int ldc,
    int act) {
  __shared__ u16 As[128 * 64];
  __shared__ u16 Ws[64 * 64];
  int tid = threadIdx.x;
  int wv = tid >> 6, lane = tid & 63;
  int m0 = blockIdx.x * 128, n0 = blockIdx.y * 64;
  floatx4 zz = {0.f, 0.f, 0.f, 0.f};
  floatx4 acc[2][4];
#pragma unroll
  for (int i = 0; i < 2; ++i)
#pragma unroll
    for (int j = 0; j < 4; ++j) acc[i][j] = zz;
  int lr = lane >> 3, ls = lane & 7;
  for (int k0 = 0; k0 < K; k0 += 64) {
#pragma unroll
    for (int i = 0; i < 4; ++i) {
      int ci = wv * 4 + i;
      int r = ci * 8 + lr;
      int cc = ls ^ (r & 7);
      GLDS16(A + (size_t)(m0 + r) * K + k0 + cc * 8, As + ci * 512);
    }
#pragma unroll
    for (int i = 0; i < 2; ++i) {
      int ci = wv * 2 + i;
      int r = ci * 8 + lr;
      int cc = ls ^ (r & 7);
      GLDS16(W + (size_t)(n0 + r) * K + k0 + cc * 8, Ws + ci * 512);
    }
    __syncthreads();
#pragma unroll
    for (int kk = 0; kk < 2; ++kk) {
      int g = kk * 4 + (lane >> 4);
      short8 a0, a1, b0, b1, b2, b3;
      {
        int row = wv * 32 + (lane & 15);
        a0 = *(const short8*)&As[row * 64 + (g ^ (row & 7)) * 8];
        int row2 = row + 16;
        a1 = *(const short8*)&As[row2 * 64 + (g ^ (row2 & 7)) * 8];
      }
      {
        int col = lane & 15;
        b0 = *(const short8*)&Ws[col * 64 + (g ^ (col & 7)) * 8];
        int c1 = col + 16;
        b1 = *(const short8*)&Ws[c1 * 64 + (g ^ (c1 & 7)) * 8];
        int c2 = col + 32;
        b2 = *(const short8*)&Ws[c2 * 64 + (g ^ (c2 & 7)) * 8];
        int c3 = col + 48;
        b3 = *(const short8*)&Ws[c3 * 64 + (g ^ (c3 & 7)) * 8];
      }
      acc[0][0] = __builtin_amdgcn_mfma_f32_16x16x32_bf16(a0, b0, acc[0][0], 0, 0, 0);
      acc[0][1] = __builtin_amdgcn_mfma_f32_16x16x32_bf16(a0, b1, acc[0][1], 0, 0, 0);
      acc[0][2] = __builtin_amdgcn_mfma_f32_16x16x32_bf16(a0, b2, acc[0][2], 0, 0, 0);
      acc[0][3] = __builtin_amdgcn_mfma_f32_16x16x32_bf16(a0, b3, acc[0][3], 0, 0, 0);
      acc[1][0] = __builtin_amdgcn_mfma_f32_16x16x32_bf16(a1, b0, acc[1][0], 0, 0, 0);
      acc[1][1] = __builtin_amdgcn_mfma_f32_16x16x32_bf16(a1, b1, acc[1][1], 0, 0, 0);
      acc[1][2] = __builtin_amdgcn_mfma_f32_16x16x32_bf16(a1, b2, acc[1][2], 0, 0, 0);
      acc[1][3] = __builtin_amdgcn_mfma_f32_16x16x32_bf16(a1, b3, acc[1][3], 0, 0, 0);
    }
    __syncthreads();
  }
  int rbase = wv * 32 + ((lane >> 4) << 2);
  int cb = lane & 15;
#pragma unroll
  for (int mi = 0; mi < 2; ++mi) {
#pragma unroll
    for (int nj = 0; nj < 4; ++nj) {
      int col = n0 + nj * 16 + cb;
      float bv = bias[col];
#pragma unroll
      for (int r = 0; r < 4; ++r) {
        int row = m0 + rbase + mi * 16 + r;
        float v = acc[mi][nj][r] + bv;
        if (act == 1) v = 0.5f * v * (1.f + erff(v * 0.70710678118654752f));
        else if (act == 2) v = silu_f(v);
        C[(size_t)row * ldc + col] = f2bf(v);
      }
    }
  }
}

// ---------------- 3x3 conv 64->64 pad1 SiLU, NHWC bf16, implicit MFMA GEMM --
__global__ __launch_bounds__(256) void conv3x3_mfma_kernel(
    const u16* __restrict__ in, int istr, u16* __restrict__ outp, int ostr,
    const u16* __restrict__ wt, const float* __restrict__ bias) {
  __shared__ u16 tile[6400];  // [100 pixels][64 c], 16B-chunk XOR swizzle
  int tid = threadIdx.x;
  int wv = tid >> 6, lane = tid & 63;
  int bx = blockIdx.x, by = blockIdx.y, b = blockIdx.z;
  int h0 = by * 8, w0 = bx * 8;
#pragma unroll
  for (int rr = 0; rr < 4; ++rr) {
    int slot = rr * 256 + tid;
    int p = slot >> 3, ch = slot & 7;
    if (p < 100) {
      int hr = p / 10, hc = p % 10;
      int gh = h0 + hr - 1, gw = w0 + hc - 1;
      bool ok = (gh >= 0) && (gh < 128) && (gw >= 0) && (gw < 128);
      uint4 v = {0u, 0u, 0u, 0u};
      if (ok) {
        size_t pix = (size_t)((b * 128 + gh) * 128 + gw);
        v = *(const uint4*)(in + pix * istr + ch * 8);
      }
      *(uint4*)(tile + p * 64 + ((ch ^ (p & 7)) << 3)) = v;
    }
  }
  __syncthreads();
  int pl = lane & 15;
  int g = lane >> 4;
  int prow = 2 * wv + (pl >> 3), pcol = pl & 7;
  floatx4 zz = {0.f, 0.f, 0.f, 0.f};
  floatx4 acc[4] = {zz, zz, zz, zz};
#pragma unroll
  for (int t = 0; t < 9; ++t) {
    int dy = t / 3, dx = t % 3;
    int hp = (prow + dy) * 10 + (pcol + dx);
    short8 bf0 = *(const short8*)&tile[hp * 64 + (((0 * 4 + g) ^ (hp & 7)) << 3)];
    short8 bf1 = *(const short8*)&tile[hp * 64 + (((1 * 4 + g) ^ (hp & 7)) << 3)];
    const u16* wtap = wt + t * 4096;
#pragma unroll
    for (int nf = 0; nf < 4; ++nf) {
      short8 a0 = *(const short8*)&wtap[(nf * 16 + pl) * 64 + g * 8];
      short8 a1 = *(const short8*)&wtap[(nf * 16 + pl) * 64 + 32 + g * 8];
      acc[nf] = __builtin_amdgcn_mfma_f32_16x16x32_bf16(a0, bf0, acc[nf], 0, 0, 0);
      acc[nf] = __builtin_amdgcn_mfma_f32_16x16x32_bf16(a1, bf1, acc[nf], 0, 0, 0);
    }
  }
  size_t pix = (size_t)((b * 128 + h0 + prow) * 128 + w0 + pcol);
#pragma unroll
  for (int nf = 0; nf < 4; ++nf) {
    float o0 = silu_f(acc[nf][0] + bias[nf * 16 + g * 4 + 0]);
    float o1 = silu_f(acc[nf][1] + bias[nf * 16 + g * 4 + 1]);
    float o2 = silu_f(acc[nf][2] + bias[nf * 16 + g * 4 + 2]);
    float o3 = silu_f(acc[nf][3] + bias[nf * 16 + g * 4 + 3]);
    uint2 w2;
    w2.x = pack2(o0, o1);
    w2.y = pack2(o2, o3);
    *(uint2*)(outp + pix * ostr + nf * 16 + g * 4) = w2;
  }
}

// ---------------- MFMA window attention -------------------------------------
// block = 1 window x 4 heads (256 thr, wave = head). Zero barriers: every LDS
// region is wave-private. No max-subtraction softmax (logits bounded <= 26).
__global__ __launch_bounds__(256) void attn_mfma_kernel(
    const u16* __restrict__ qkv, const float* __restrict__ logit_scale,
    const float* __restrict__ bias_t, u16* __restrict__ ao) {
  __shared__ __align__(16) char lds[4 * 10240 + 4 * 4608];  // 59392 B
  int tid = threadIdx.x;
  int w = tid >> 6, l = tid & 63;
  int wid = blockIdx.x >> 1;
  int h = __builtin_amdgcn_readfirstlane(((blockIdx.x & 1) << 2) + w);
  char* Aq = lds + w * 10240;         // qs [64][40] u16 (rows 80B)
  char* Ak = Aq + 5120;               // ks [64][40] u16
  char* Pt = Aq;                      // pt [64][72] u16 (overlay, rows 144B)
  char* Vt = lds + 40960 + w * 4608;  // vt [32][72] u16 (rows 144B)
  char* Ol = Vt;                      // o  [64][36] u16 (overlay, rows 72B)

  int b = wid >> 8, wh = (wid >> 4) & 15, ww = wid & 15;
  int p = (b << 14) + ((wh * 8 + (l >> 3)) << 7) + ww * 8 + (l & 7);
  const u32* qp = (const u32*)(qkv + (size_t)p * 768 + h * 32);
  float scale = __expf(fminf(logit_scale[h], 4.6051701860f));
  int lc = l & 15, lg = l >> 4;

  // ---- stage Q (scaled+normalized), K (normalized), V^T ----
  {
    float f[32];
    float s = 0.f;
#pragma unroll
    for (int i = 0; i < 16; ++i) {
      u32 u = qp[i];
      f[2 * i] = bflo(u);
      f[2 * i + 1] = bfhi(u);
    }
#pragma unroll
    for (int d = 0; d < 32; ++d) s += f[d] * f[d];
    float r = scale / fmaxf(sqrtf(s), 1e-12f);
    uint4* dst = (uint4*)(Aq + l * 80);
#pragma unroll
    for (int c = 0; c < 4; ++c) {
      uint4 v;
      v.x = pack2(f[c * 8 + 0] * r, f[c * 8 + 1] * r);
      v.y = pack2(f[c * 8 + 2] * r, f[c * 8 + 3] * r);
      v.z = pack2(f[c * 8 + 4] * r, f[c * 8 + 5] * r);
      v.w = pack2(f[c * 8 + 6] * r, f[c * 8 + 7] * r);
      dst[c] = v;
    }
  }
  {
    float f[32];
    float s = 0.f;
#pragma unroll
    for (int i = 0; i < 16; ++i) {
      u32 u = qp[128 + i];
      f[2 * i] = bflo(u);
      f[2 * i + 1] = bfhi(u);
    }
#pragma unroll
    for (int d = 0; d < 32; ++d) s += f[d] * f[d];
    float r = 1.f / fmaxf(sqrtf(s), 1e-12f);
    uint4* dst = (uint4*)(Ak + l * 80);
#pragma unroll
    for (int c = 0; c < 4; ++c) {
      uint4 v;
      v.x = pack2(f[c * 8 + 0] * r, f[c * 8 + 1] * r);
      v.y = pack2(f[c * 8 + 2] * r, f[c * 8 + 3] * r);
      v.z = pack2(f[c * 8 + 4] * r, f[c * 8 + 5] * r);
      v.w = pack2(f[c * 8 + 6] * r, f[c * 8 + 7] * r);
      dst[c] = v;
    }
  }
  {
#pragma unroll
    for (int i = 0; i < 16; ++i) {
      u32 u = qp[256 + i];
      *(u16*)(Vt + (2 * i) * 144 + l * 2) = (u16)(u & 0xffffu);
      *(u16*)(Vt + (2 * i + 1) * 144 + l * 2) = (u16)(u >> 16);
    }
  }

  // ---- S^T = Kn @ Qs^T : S[m][n], m from K (rows), n from Q (cols) ----
  short8 kf[4], qf[4];
#pragma unroll
  for (int i = 0; i < 4; ++i) {
    kf[i] = *(const short8*)(Ak + (i * 16 + lc) * 80 + (lg << 4));
    qf[i] = *(const short8*)(Aq + (i * 16 + lc) * 80 + (lg << 4));
  }
  floatx4 zz = {0.f, 0.f, 0.f, 0.f};
  floatx4 S[4][4];
#pragma unroll
  for (int mi = 0; mi < 4; ++mi)
#pragma unroll
    for (int ni = 0; ni < 4; ++ni) S[mi][ni] = zz;
#pragma unroll
  for (int mi = 0; mi < 4; ++mi)
#pragma unroll
    for (int ni = 0; ni < 4; ++ni)
      S[mi][ni] = __builtin_amdgcn_mfma_f32_16x16x32_bf16(kf[mi], qf[ni], S[mi][ni], 0, 0, 0);

  // ---- softmax over m (no max-subtraction; logits <= 26) ----
  const float* bh = bias_t + h * 4096;
  float den[4] = {0.f, 0.f, 0.f, 0.f};
#pragma unroll
  for (int mi = 0; mi < 4; ++mi) {
    int mb = mi * 16 + (lg << 2);
#pragma unroll
    for (int ni = 0; ni < 4; ++ni) {
      int nn = ni * 16 + lc;
#pragma unroll
      for (int r = 0; r < 4; ++r) {
        float e = __expf(S[mi][ni][r] + bh[(mb + r) * 64 + nn]);
        S[mi][ni][r] = e;
        den[ni] += e;
      }
    }
  }
#pragma unroll
  for (int ni = 0; ni < 4; ++ni) {
    den[ni] += __shfl_xor(den[ni], 16);
    den[ni] += __shfl_xor(den[ni], 32);
    den[ni] = 1.f / den[ni];
  }

  // ---- P (inv folded) -> bf16 -> Pt[n][m] (overlays Aq/Ak) ----
#pragma unroll
  for (int ni = 0; ni < 4; ++ni)
#pragma unroll
    for (int mi = 0; mi < 4; ++mi) {
      uint2 v;
      v.x = pack2(S[mi][ni][0] * den[ni], S[mi][ni][1] * den[ni]);
      v.y = pack2(S[mi][ni][2] * den[ni], S[mi][ni][3] * den[ni]);
      *(uint2*)(Pt + (ni * 16 + lc) * 144 + mi * 32 + (lg << 3)) = v;
    }

  // ---- O = P @ V : O[n][d] ----
  short8 vf[2][2];
#pragma unroll
  for (int ks = 0; ks < 2; ++ks)
#pragma unroll
    for (int db = 0; db < 2; ++db)
      vf[ks][db] = *(const short8*)(Vt + (db * 16 + lc) * 144 + ks * 64 + (lg << 4));
  floatx4 O[4][2];
#pragma unroll
  for (int nb = 0; nb < 4; ++nb) {
    O[nb][0] = zz;
    O[nb][1] = zz;
  }
#pragma unroll
  for (int nb = 0; nb < 4; ++nb) {
    short8 pf0 = *(const short8*)(Pt + (nb * 16 + lc) * 144 + (lg << 4));
    short8 pf1 = *(const short8*)(Pt + (nb * 16 + lc) * 144 + 64 + (lg << 4));
    O[nb][0] = __builtin_amdgcn_mfma_f32_16x16x32_bf16(pf0, vf[0][0], O[nb][0], 0, 0, 0);
    O[nb][0] = __builtin_amdgcn_mfma_f32_16x16x32_bf16(pf1, vf[1][0], O[nb][0], 0, 0, 0);
    O[nb][1] = __builtin_amdgcn_mfma_f32_16x16x32_bf16(pf0, vf[0][1], O[nb][1], 0, 0, 0);
    O[nb][1] = __builtin_amdgcn_mfma_f32_16x16x32_bf16(pf1, vf[1][1], O[nb][1], 0, 0, 0);
  }

  // ---- O -> Ol[n][d] (overlays Vt) -> coalesced global store ----
#pragma unroll
  for (int nb = 0; nb < 4; ++nb)
#pragma unroll
    for (int r = 0; r < 4; ++r) {
      int n = nb * 16 + (lg << 2) + r;
      *(u16*)(Ol + n * 72 + lc * 2) = f2bf(O[nb][0][r]);
      *(u16*)(Ol + n * 72 + (16 + lc) * 2) = f2bf(O[nb][1][r]);
    }
  u32 ov[16];
#pragma unroll
  for (int j = 0; j < 16; ++j) ov[j] = *(const u32*)(Ol + l * 72 + j * 4);
  uint4* op = (uint4*)(ao + (size_t)(wid * 64 + l) * 256 + h * 32);
#pragma unroll
  for (int q4 = 0; q4 < 4; ++q4) {
    uint4 v;
    v.x = ov[q4 * 4 + 0];
    v.y = ov[q4 * 4 + 1];
    v.z = ov[q4 * 4 + 2];
    v.w = ov[q4 * 4 + 3];
    op[q4] = v;
  }
}

// ---------------- LN1: SBF = bf16( EBF + LN(P) ), vectorized ----------------
// P token-major, EBF/SBF pixel-major. thread = (pixel-in-64-group, c-quarter).
__global__ __launch_bounds__(256) void ln1v_kernel(
    const u16* __restrict__ pin, const u16* __restrict__ ebf,
    u16* __restrict__ sbf, const float* __restrict__ g,
    const float* __restrict__ bb) {
  int tid = threadIdx.x;
  int bid = blockIdx.x;  // 1024 = b(4) x 256 groups of 64 pixels
  int b = bid >> 8, hw0 = (bid & 255) << 6;
  int i = tid >> 2, qq = tid & 3;
  int hw = hw0 + i;
  int him = hw >> 7, wim = hw & 127;
  int wid = b * 256 + (him >> 3) * 16 + (wim >> 3);
  int t = wid * 64 + (him & 7) * 8 + (wim & 7);
  size_t pbase = (size_t)t * 256 + qq * 64;
  size_t ebase = ((size_t)(b * HW + hw)) * 256 + qq * 64;
  float v[64];
  float s1 = 0.f, s2 = 0.f;
#pragma unroll
  for (int j = 0; j < 8; ++j) {
    uint4 u = *(const uint4*)(pin + pbase + j * 8);
    u32 ua[4] = {u.x, u.y, u.z, u.w};
#pragma unroll
    for (int k = 0; k < 4; ++k) {
      float a = bflo(ua[k]), c = bfhi(ua[k]);
      v[j * 8 + 2 * k] = a;
      v[j * 8 + 2 * k + 1] = c;
      s1 += a + c;
      s2 += a * a + c * c;
    }
  }
  s1 += __shfl_xor(s1, 1);
  s1 += __shfl_xor(s1, 2);
  s2 += __shfl_xor(s2, 1);
  s2 += __shfl_xor(s2, 2);
  float mean = s1 * (1.f / 256.f);
  float var = s2 * (1.f / 256.f) - mean * mean;
  float rs = rsqrtf(var + 1e-5f);
#pragma unroll
  for (int j = 0; j < 8; ++j) {
    uint4 u = *(const uint4*)(ebf + ebase + j * 8);
    u32 ua[4] = {u.x, u.y, u.z, u.w};
    uint4 o;
    u32 ow[4];
#pragma unroll
    for (int k = 0; k < 4; ++k) {
      int c = qq * 64 + j * 8 + 2 * k;
      float o0 = bflo(ua[k]) + (v[j * 8 + 2 * k] - mean) * rs * g[c] + bb[c];
      float o1 = bfhi(ua[k]) + (v[j * 8 + 2 * k + 1] - mean) * rs * g[c + 1] + bb[c + 1];
      ow[k] = pack2(o0, o1);
    }
    o.x = ow[0]; o.y = ow[1]; o.z = ow[2]; o.w = ow[3];
    *(uint4*)(sbf + ebase + j * 8) = o;
  }
}

// ---------------- LN2 + residual + NHWC->NCHW store fused -------------------
__global__ __launch_bounds__(256) void ln2t_kernel(
    const u16* __restrict__ h2, const u16* __restrict__ sbf,
    const float* __restrict__ g, const float* __restrict__ bb,
    float* __restrict__ outp) {
  __shared__ float tile[64][257];
  int tid = threadIdx.x;
  int bid = blockIdx.x;  // 1024 = b(4) x 256 groups
  int b = bid >> 8, hw0 = (bid & 255) << 6;
  int i = tid >> 2, qq = tid & 3;
  size_t base = ((size_t)(b * HW + hw0 + i)) * 256 + qq * 64;
  float v[64];
  float s1 = 0.f, s2 = 0.f;
#pragma unroll
  for (int j = 0; j < 8; ++j) {
    uint4 u = *(const uint4*)(h2 + base + j * 8);
    u32 ua[4] = {u.x, u.y, u.z, u.w};
#pragma unroll
    for (int k = 0; k < 4; ++k) {
      float a = bflo(ua[k]), c = bfhi(ua[k]);
      v[j * 8 + 2 * k] = a;
      v[j * 8 + 2 * k + 1] = c;
      s1 += a + c;
      s2 += a * a + c * c;
    }
  }
  s1 += __shfl_xor(s1, 1);
  s1 += __shfl_xor(s1, 2);
  s2 += __shfl_xor(s2, 1);
  s2 += __shfl_xor(s2, 2);
  float mean = s1 * (1.f / 256.f);
  float var = s2 * (1.f / 256.f) - mean * mean;
  float rs = rsqrtf(var + 1e-5f);
#pragma unroll
  for (int j = 0; j < 8; ++j) {
    uint4 u = *(const uint4*)(sbf + base + j * 8);
    u32 ua[4] = {u.x, u.y, u.z, u.w};
#pragma unroll
    for (int k = 0; k < 4; ++k) {
      int c = qq * 64 + j * 8 + 2 * k;
      tile[i][c] = bflo(ua[k]) + (v[j * 8 + 2 * k] - mean) * rs * g[c] + bb[c];
      tile[i][c + 1] = bfhi(ua[k]) + (v[j * 8 + 2 * k + 1] - mean) * rs * g[c + 1] + bb[c + 1];
    }
  }
  __syncthreads();
  int pl = tid & 63, cq = tid >> 6;
#pragma unroll 8
  for (int cc = 0; cc < 64; ++cc) {
    int c = cq * 64 + cc;
    outp[((size_t)(b * 256 + c)) * HW + hw0 + pl] = tile[pl][c];
  }
}

// ---------------------------------------------------------------------------
extern "C" void kernel_launch(void* const* d_in, const int* in_sizes, int n_in,
                              void* d_out, int out_size, void* d_ws, size_t ws_size,
                              hipStream_t stream) {
  const float* x        = (const float*)d_in[0];
  const float* w_stem   = (const float*)d_in[1];
  const float* s_stem   = (const float*)d_in[2];
  const float* b_stem   = (const float*)d_in[3];
  const float* w_blk    = (const float*)d_in[4];
  const float* s_blk    = (const float*)d_in[5];
  const float* b_blk    = (const float*)d_in[6];
  const float* norm1_g  = (const float*)d_in[7];
  const float* norm1_b  = (const float*)d_in[8];
  const float* qkv_w    = (const float*)d_in[9];
  const float* qkv_b    = (const float*)d_in[10];
  const float* proj_w   = (const float*)d_in[11];
  const float* proj_b   = (const float*)d_in[12];
  const float* logit_sc = (const float*)d_in[13];
  const float* cpb_w1   = (const float*)d_in[14];
  const float* cpb_b1   = (const float*)d_in[15];
  const float* cpb_w2   = (const float*)d_in[16];
  const float* norm2_g  = (const float*)d_in[17];
  const float* norm2_b  = (const float*)d_in[18];
  const float* mlp_w1   = (const float*)d_in[19];
  const float* mlp_b1   = (const float*)d_in[20];
  const float* mlp_w2   = (const float*)d_in[21];
  const float* mlp_b2   = (const float*)d_in[22];
  float* out = (float*)d_out;
  float* ws = (float*)d_ws;
  (void)in_sizes; (void)n_in; (void)out_size; (void)ws_size;

  // ---- workspace regions (floats) ----
  float* R0 = ws;                  // 16,777,216
  float* R1 = ws + 16777216;       // 16,777,216
  float* R2 = ws + 33554432;       // 16,777,216
  float* TAIL = ws + 50331648;
  u16* WTC  = (u16*)TAIL;                    // 147,456 u16
  u16* WTS  = (u16*)(TAIL + 73728);          // 16,384 u16
  u16* QWB  = (u16*)(TAIL + 81920);          // 196,608 u16
  u16* PWB  = (u16*)(TAIL + 180224);         // 65,536 u16
  u16* M1WB = (u16*)(TAIL + 212992);
  u16* M2WB = (u16*)(TAIL + 245760);
  float* BPRE = TAIL + 278528;               // 2,048 f
  float* BFT  = TAIL + 280576;               // 32,768 f

  // phase overlays (lifetimes disjoint):
  u16* XT  = (u16*)R2;               // [65536][128] bf16, dead after stem gemm
  u16* EBF = (u16*)(R2 + 8388608);   // [65536][256] bf16 NHWC e; lives to ln1
  u16* T1  = (u16*)R1;               // conv intermediates
  u16* T2  = (u16*)(R1 + 2097152);
  u16* QKV = (u16*)R1;               // [65536][768] = R1 full + R2[0:8.39M f)
  u16* AO  = (u16*)R0;               // attn out [65536][256] token-major
  u16* P   = (u16*)(R0 + 8388608);   // proj out token-major
  u16* SBF = (u16*)R0;               // S bf16 pixel-major (over AO)
  u16* Hb  = (u16*)R2;               // mlp hidden (over QKV tail / dead XT)
  u16* H2  = (u16*)(R0 + 8388608);   // mlp out (over P)

  // ---- param prep ----
  repack_kernel<<<640, 256, 0, stream>>>(w_blk, s_blk, w_stem, s_stem, WTC, WTS);
  castw_kernel<<<768, 256, 0, stream>>>(qkv_w, QWB, 196608);
  castw_kernel<<<256, 256, 0, stream>>>(proj_w, PWB, 65536);
  castw_kernel<<<256, 256, 0, stream>>>(mlp_w1, M1WB, 65536);
  castw_kernel<<<256, 256, 0, stream>>>(mlp_w2, M2WB, 65536);
  cpb_mlp_kernel<<<225, 512, 0, stream>>>(cpb_w1, cpb_b1, cpb_w2, BPRE);
  cpb_expand_kernel<<<16, 256, 0, stream>>>(BPRE, BFT);

  // ---- input transpose + stem (1x1 conv = GEMM, SiLU) -> EBF ch 128..255 ----
  transpose_in_kernel<<<2048, 256, 0, stream>>>(x, XT);
  dim3 gs(512, 2);
  gemm_bf16_kernel<<<gs, 256, 0, stream>>>(XT, WTS, b_stem, EBF + 128, 128, 256, 2);

  // ---- ELAN 3x3 convs (bf16 MFMA implicit GEMM) ----
  dim3 cgrid(16, 16, 4);
  conv3x3_mfma_kernel<<<cgrid, 256, 0, stream>>>(EBF + 128, 256, T1, 64, WTC, b_blk);
  conv3x3_mfma_kernel<<<cgrid, 256, 0, stream>>>(T1, 64, EBF + 64, 256, WTC + 9 * 4096, b_blk + 64);
  conv3x3_mfma_kernel<<<cgrid, 256, 0, stream>>>(EBF + 64, 256, T2, 64, WTC + 18 * 4096, b_blk + 128);
  conv3x3_mfma_kernel<<<cgrid, 256, 0, stream>>>(T2, 64, EBF, 256, WTC + 27 * 4096, b_blk + 192);

  // ---- qkv GEMM (bf16 MFMA) ----
  dim3 gq(512, 12);
  gemm_bf16_kernel<<<gq, 256, 0, stream>>>(EBF, QWB, qkv_b, QKV, 256, 768, 0);

  // ---- MFMA window attention ----
  attn_mfma_kernel<<<2048, 256, 0, stream>>>(QKV, logit_sc, BFT, AO);

  // ---- proj + LN1 + MLP + LN2(+transpose) ----
  dim3 g4(512, 4);
  gemm_bf16_kernel<<<g4, 256, 0, stream>>>(AO, PWB, proj_b, P, 256, 256, 0);
  ln1v_kernel<<<1024, 256, 0, stream>>>(P, EBF, SBF, norm1_g, norm1_b);
  gemm_bf16_kernel<<<g4, 256, 0, stream>>>(SBF, M1WB, mlp_b1, Hb, 256, 256, 1);
  gemm_bf16_kernel<<<g4, 256, 0, stream>>>(Hb, M2WB, mlp_b2, H2, 256, 256, 0);
  ln2t_kernel<<<1024, 256, 0, stream>>>(H2, SBF, norm2_g, norm2_b, out);
}

// Round 8
// 443.162 us; speedup vs baseline: 5.4490x; 1.0478x over previous
//
#include <hip/hip_runtime.h>
#include <hip/hip_bf16.h>
#include <math.h>

// ---------------------------------------------------------------------------
// ELAN + SwinV2: bf16 MFMA convs + GEMMs; fused qkv+attention (hi/lo QK^T);
// R4-verified separate proj/ln1/mlp/ln2 chain (gemm_ln reverted for diagnosis).
// B=4, C_IN=128, H=W=128, DIM=256, WS=8, HEADS=8, HEAD_DIM=32.
// ---------------------------------------------------------------------------

#define HW 16384
typedef unsigned int u32;
typedef unsigned short u16;
typedef __attribute__((ext_vector_type(8))) short short8;   // bf16x8 MFMA frag
typedef __attribute__((ext_vector_type(4))) float floatx4;  // f32x4 acc frag

// compiler-only fence: blocks LDS load/store reordering (HW is in-order per wave)
#define MEMBAR() asm volatile("" ::: "memory")

__device__ __forceinline__ float silu_f(float y) { return y / (1.f + expf(-y)); }
__device__ __forceinline__ float bflo(u32 u) { return __uint_as_float(u << 16); }
__device__ __forceinline__ float bfhi(u32 u) { return __uint_as_float(u & 0xffff0000u); }
__device__ __forceinline__ float bf2f(u16 v) { return __uint_as_float((u32)v << 16); }
__device__ __forceinline__ u16 f2bf(float x) {
  u32 u = __float_as_uint(x);
  u += 0x7fffu + ((u >> 16) & 1u);
  return (u16)(u >> 16);
}
__device__ __forceinline__ u32 pack2(float a, float b) {
  return (u32)f2bf(a) | ((u32)f2bf(b) << 16);
}

#define GLDS16(gp, lp)                                           \
  __builtin_amdgcn_global_load_lds(                              \
      (const __attribute__((address_space(1))) void*)(gp),       \
      (__attribute__((address_space(3))) void*)(lp), 16, 0, 0)

// ---------------- weight repack: conv weights -> bf16, BN scale folded ------
__global__ __launch_bounds__(256) void repack_kernel(
    const float* __restrict__ w_blk, const float* __restrict__ s_blk,
    const float* __restrict__ w_stem, const float* __restrict__ s_stem,
    u16* __restrict__ wtc, u16* __restrict__ wts) {
  int idx = blockIdx.x * 256 + threadIdx.x;
  if (idx < 147456) {
    int c = idx & 63;
    int rest = idx >> 6;
    int oc = rest & 63;
    int ct = rest >> 6;
    int conv = ct / 9, t = ct % 9;
    float w = w_blk[((size_t)(conv * 64 + oc) * 64 + c) * 9 + t];
    wtc[idx] = f2bf(w * s_blk[conv * 64 + oc]);
  } else if (idx < 147456 + 16384) {
    int j = idx - 147456;
    int c = j & 127, oc = j >> 7;
    float w = w_stem[(size_t)oc * 128 + c];
    wts[j] = f2bf(w * s_stem[oc]);
  }
}

__global__ __launch_bounds__(256) void castw_kernel(
    const float* __restrict__ in, u16* __restrict__ outp, int n) {
  int i = blockIdx.x * 256 + threadIdx.x;
  if (i < n) outp[i] = f2bf(in[i]);
}

// ---------------- continuous position bias MLP -----------------------------
__global__ __launch_bounds__(512) void cpb_mlp_kernel(
    const float* __restrict__ w1, const float* __restrict__ b1,
    const float* __restrict__ w2, float* __restrict__ pre) {
  __shared__ float hb[512];
  int t = blockIdx.x, j = threadIdx.x;
  int i = t / 15, jj = t % 15;
  float c0 = (float)(i - 7) * (8.f / 7.f);
  float c1 = (float)(jj - 7) * (8.f / 7.f);
  float s0 = (c0 > 0.f) ? 1.f : ((c0 < 0.f) ? -1.f : 0.f);
  float s1 = (c1 > 0.f) ? 1.f : ((c1 < 0.f) ? -1.f : 0.f);
  float t0 = s0 * log2f(fabsf(c0) + 1.f) * (1.f / 3.f);
  float t1 = s1 * log2f(fabsf(c1) + 1.f) * (1.f / 3.f);
  float h = t0 * w1[j * 2] + t1 * w1[j * 2 + 1] + b1[j];
  hb[j] = fmaxf(h, 0.f);
  __syncthreads();
  if (j < 8) {
    float s = 0.f;
    for (int k = 0; k < 512; ++k) s += hb[k] * w2[j * 512 + k];
    pre[t * 8 + j] = s;
  }
}

// bias_t[h][m][n]: bias for (key m, query n)
__global__ __launch_bounds__(256) void cpb_expand_kernel(
    const float* __restrict__ pre, float* __restrict__ bias_t) {
  int idx = blockIdx.x * 256 + threadIdx.x;
  int m = idx >> 6, n = idx & 63;
  int di = (n >> 3) - (m >> 3) + 7;
  int dj = (n & 7) - (m & 7) + 7;
  int ti = di * 15 + dj;
#pragma unroll
  for (int h = 0; h < 8; ++h) {
    float v = pre[ti * 8 + h];
    bias_t[h * 4096 + idx] = 16.f / (1.f + expf(-v));
  }
}

// ---------------- x NCHW fp32 -> XT NHWC bf16 -------------------------------
__global__ __launch_bounds__(256) void transpose_in_kernel(
    const float* __restrict__ x, u16* __restrict__ xt) {
  __shared__ float tl[64][65];
  int bid = blockIdx.x;
  int b = bid >> 9;
  int r = bid & 511;
  int cs = r >> 8, hws = r & 255;
  int c0 = cs << 6, hw0 = hws << 6;
  int tid = threadIdx.x;
  for (int e = tid; e < 4096; e += 256) {
    int c = e >> 6, p = e & 63;
    tl[c][p] = x[(size_t)(b * 128 + c0 + c) * HW + hw0 + p];
  }
  __syncthreads();
  for (int e = tid; e < 4096; e += 256) {
    int p = e >> 6, c = e & 63;
    xt[(size_t)(b * HW + hw0 + p) * 128 + c0 + c] = f2bf(tl[c][p]);
  }
}

// ---------------- bf16 MFMA GEMM: C[.,col]=act(A[M,K] @ W[N,K]^T + b) -------
__global__ __launch_bounds__(256, 4) void gemm_bf16_kernel(
    const u16* __restrict__ A, const u16* __restrict__ W,
    const float* __restrict__ bias, u16* __restrict__ C, int K, int ldc,
    int act) {
  __shared__ u16 As[128 * 64];
  __shared__ u16 Ws[64 * 64];
  int tid = threadIdx.x;
  int wv = tid >> 6, lane = tid & 63;
  int m0 = blockIdx.x * 128, n0 = blockIdx.y * 64;
  floatx4 zz = {0.f, 0.f, 0.f, 0.f};
  floatx4 acc[2][4];
#pragma unroll
  for (int i = 0; i < 2; ++i)
#pragma unroll
    for (int j = 0; j < 4; ++j) acc[i][j] = zz;
  int lr = lane >> 3, ls = lane & 7;
  for (int k0 = 0; k0 < K; k0 += 64) {
#pragma unroll
    for (int i = 0; i < 4; ++i) {
      int ci = wv * 4 + i;
      int r = ci * 8 + lr;
      int cc = ls ^ (r & 7);
      GLDS16(A + (size_t)(m0 + r) * K + k0 + cc * 8, As + ci * 512);
    }
#pragma unroll
    for (int i = 0; i < 2; ++i) {
      int ci = wv * 2 + i;
      int r = ci * 8 + lr;
      int cc = ls ^ (r & 7);
      GLDS16(W + (size_t)(n0 + r) * K + k0 + cc * 8, Ws + ci * 512);
    }
    __syncthreads();
#pragma unroll
    for (int kk = 0; kk < 2; ++kk) {
      int g = kk * 4 + (lane >> 4);
      short8 a0, a1, b0, b1, b2, b3;
      {
        int row = wv * 32 + (lane & 15);
        a0 = *(const short8*)&As[row * 64 + (g ^ (row & 7)) * 8];
        int row2 = row + 16;
        a1 = *(const short8*)&As[row2 * 64 + (g ^ (row2 & 7)) * 8];
      }
      {
        int col = lane & 15;
        b0 = *(const short8*)&Ws[col * 64 + (g ^ (col & 7)) * 8];
        int c1 = col + 16;
        b1 = *(const short8*)&Ws[c1 * 64 + (g ^ (c1 & 7)) * 8];
        int c2 = col + 32;
        b2 = *(const short8*)&Ws[c2 * 64 + (g ^ (c2 & 7)) * 8];
        int c3 = col + 48;
        b3 = *(const short8*)&Ws[c3 * 64 + (g ^ (c3 & 7)) * 8];
      }
      acc[0][0] = __builtin_amdgcn_mfma_f32_16x16x32_bf16(a0, b0, acc[0][0], 0, 0, 0);
      acc[0][1] = __builtin_amdgcn_mfma_f32_16x16x32_bf16(a0, b1, acc[0][1], 0, 0, 0);
      acc[0][2] = __builtin_amdgcn_mfma_f32_16x16x32_bf16(a0, b2, acc[0][2], 0, 0, 0);
      acc[0][3] = __builtin_amdgcn_mfma_f32_16x16x32_bf16(a0, b3, acc[0][3], 0, 0, 0);
      acc[1][0] = __builtin_amdgcn_mfma_f32_16x16x32_bf16(a1, b0, acc[1][0], 0, 0, 0);
      acc[1][1] = __builtin_amdgcn_mfma_f32_16x16x32_bf16(a1, b1, acc[1][1], 0, 0, 0);
      acc[1][2] = __builtin_amdgcn_mfma_f32_16x16x32_bf16(a1, b2, acc[1][2], 0, 0, 0);
      acc[1][3] = __builtin_amdgcn_mfma_f32_16x16x32_bf16(a1, b3, acc[1][3], 0, 0, 0);
    }
    __syncthreads();
  }
  int rbase = wv * 32 + ((lane >> 4) << 2);
  int cb = lane & 15;
#pragma unroll
  for (int mi = 0; mi < 2; ++mi) {
#pragma unroll
    for (int nj = 0; nj < 4; ++nj) {
      int col = n0 + nj * 16 + cb;
      float bv = bias[col];
#pragma unroll
      for (int r = 0; r < 4; ++r) {
        int row = m0 + rbase + mi * 16 + r;
        float v = acc[mi][nj][r] + bv;
        if (act == 1) v = 0.5f * v * (1.f + erff(v * 0.70710678118654752f));
        else if (act == 2) v = silu_f(v);
        C[(size_t)row * ldc + col] = f2bf(v);
      }
    }
  }
}

// ---------------- 3x3 conv 64->64 pad1 SiLU, NHWC bf16, implicit MFMA GEMM --
__global__ __launch_bounds__(256) void conv3x3_mfma_kernel(
    const u16* __restrict__ in, int istr, u16* __restrict__ outp, int ostr,
    const u16* __restrict__ wt, const float* __restrict__ bias) {
  __shared__ u16 tile[6400];
  int tid = threadIdx.x;
  int wv = tid >> 6, lane = tid & 63;
  int bx = blockIdx.x, by = blockIdx.y, b = blockIdx.z;
  int h0 = by * 8, w0 = bx * 8;
#pragma unroll
  for (int rr = 0; rr < 4; ++rr) {
    int slot = rr * 256 + tid;
    int p = slot >> 3, ch = slot & 7;
    if (p < 100) {
      int hr = p / 10, hc = p % 10;
      int gh = h0 + hr - 1, gw = w0 + hc - 1;
      bool ok = (gh >= 0) && (gh < 128) && (gw >= 0) && (gw < 128);
      uint4 v = {0u, 0u, 0u, 0u};
      if (ok) {
        size_t pix = (size_t)((b * 128 + gh) * 128 + gw);
        v = *(const uint4*)(in + pix * istr + ch * 8);
      }
      *(uint4*)(tile + p * 64 + ((ch ^ (p & 7)) << 3)) = v;
    }
  }
  __syncthreads();
  int pl = lane & 15;
  int g = lane >> 4;
  int prow = 2 * wv + (pl >> 3), pcol = pl & 7;
  floatx4 zz = {0.f, 0.f, 0.f, 0.f};
  floatx4 acc[4] = {zz, zz, zz, zz};
#pragma unroll
  for (int t = 0; t < 9; ++t) {
    int dy = t / 3, dx = t % 3;
    int hp = (prow + dy) * 10 + (pcol + dx);
    short8 bf0 = *(const short8*)&tile[hp * 64 + (((0 * 4 + g) ^ (hp & 7)) << 3)];
    short8 bf1 = *(const short8*)&tile[hp * 64 + (((1 * 4 + g) ^ (hp & 7)) << 3)];
    const u16* wtap = wt + t * 4096;
#pragma unroll
    for (int nf = 0; nf < 4; ++nf) {
      short8 a0 = *(const short8*)&wtap[(nf * 16 + pl) * 64 + g * 8];
      short8 a1 = *(const short8*)&wtap[(nf * 16 + pl) * 64 + 32 + g * 8];
      acc[nf] = __builtin_amdgcn_mfma_f32_16x16x32_bf16(a0, bf0, acc[nf], 0, 0, 0);
      acc[nf] = __builtin_amdgcn_mfma_f32_16x16x32_bf16(a1, bf1, acc[nf], 0, 0, 0);
    }
  }
  size_t pix = (size_t)((b * 128 + h0 + prow) * 128 + w0 + pcol);
#pragma unroll
  for (int nf = 0; nf < 4; ++nf) {
    float o0 = silu_f(acc[nf][0] + bias[nf * 16 + g * 4 + 0]);
    float o1 = silu_f(acc[nf][1] + bias[nf * 16 + g * 4 + 1]);
    float o2 = silu_f(acc[nf][2] + bias[nf * 16 + g * 4 + 2]);
    float o3 = silu_f(acc[nf][3] + bias[nf * 16 + g * 4 + 3]);
    uint2 w2;
    w2.x = pack2(o0, o1);
    w2.y = pack2(o2, o3);
    *(uint2*)(outp + pix * ostr + nf * 16 + g * 4) = w2;
  }
}

// ---------------- fused qkv-GEMM + window attention --------------------------
__device__ __forceinline__ void qkv_mm(const u16* Elds, const u16* qwb,
                                       int moff, int h, int lc, int lg,
                                       floatx4 acc[4][2]) {
  floatx4 zz = {0.f, 0.f, 0.f, 0.f};
#pragma unroll
  for (int mf = 0; mf < 4; ++mf) {
    acc[mf][0] = zz;
    acc[mf][1] = zz;
  }
#pragma unroll
  for (int ks = 0; ks < 8; ++ks) {
    int ch = ks >> 1, g = ((ks & 1) << 2) + lg;
    short8 af[4];
#pragma unroll
    for (int mf = 0; mf < 4; ++mf) {
      int tk = mf * 16 + lc;
      af[mf] = *(const short8*)&Elds[(ch * 64 + tk) * 64 + ((g ^ (tk & 7)) << 3)];
    }
#pragma unroll
    for (int nf = 0; nf < 2; ++nf) {
      short8 bf = *(const short8*)(qwb +
          (size_t)(moff + h * 32 + nf * 16 + lc) * 256 + ks * 32 + lg * 8);
#pragma unroll
      for (int mf = 0; mf < 4; ++mf)
        acc[mf][nf] =
            __builtin_amdgcn_mfma_f32_16x16x32_bf16(af[mf], bf, acc[mf][nf], 0, 0, 0);
    }
  }
}

__global__ __launch_bounds__(256) void attn_fused_kernel(
    const u16* __restrict__ ebf, const u16* __restrict__ qwb,
    const float* __restrict__ qkv_b, const float* __restrict__ logit_scale,
    const float* __restrict__ bias_t, u16* __restrict__ ao) {
  __shared__ __align__(16) char lds[73728];
  int tid = threadIdx.x;
  int w = tid >> 6, l = tid & 63;
  int wid = blockIdx.x >> 1;
  int h = __builtin_amdgcn_readfirstlane(((blockIdx.x & 1) << 2) + w);
  u16* Elds = (u16*)lds;               // [4 chunks][64 rows][64] swizzled
  char* Kn = lds + 32768 + w * 10240;  // [64][40] u16 (hi, then lo in place)
  char* Qn = Kn + 5120;                // [64][40] u16
  char* Pt = Kn;                       // overlay [64][72] u16 rows 144B
  char* Vt = lds + w * 4608;           // overlay E region after barrier
  char* Ol = Vt;                       // [64][36] u16 rows 72B

  int b = wid >> 8, wh = (wid >> 4) & 15, ww = wid & 15;
  int pixbase = (b << 14) + wh * 1024 + ww * 8;
  {  // stage E window: wave w stages chunk w (k-cols w*64..w*64+63)
    int lr = l >> 3, ls = l & 7;
#pragma unroll
    for (int j = 0; j < 8; ++j) {
      int pix = pixbase + j * 128 + lr;
      GLDS16(ebf + (size_t)pix * 256 + w * 64 + ((ls ^ lr) << 3),
             Elds + (w * 8 + j) * 512);
    }
  }
  __syncthreads();

  int lc = l & 15, lg = l >> 4;
  float scale = __expf(fminf(logit_scale[h], 4.6051701860f));
  floatx4 macc[4][2];
  float rnrm[4][4];
  short8 kf_hi[4], kf_lo[4], qf_hi[4], qf_lo[4];

  // ---- K: project, normalize; hi -> LDS -> frags; lo (register) -> frags ----
  qkv_mm(Elds, qwb, 256, h, lc, lg, macc);
#pragma unroll
  for (int mf = 0; mf < 4; ++mf)
#pragma unroll
    for (int r = 0; r < 4; ++r) {
      float v0 = macc[mf][0][r], v1 = macc[mf][1][r];
      float ss = v0 * v0 + v1 * v1;
      ss += __shfl_xor(ss, 1);
      ss += __shfl_xor(ss, 2);
      ss += __shfl_xor(ss, 4);
      ss += __shfl_xor(ss, 8);
      float rk = 1.f / fmaxf(sqrtf(ss), 1e-12f);
      rnrm[mf][r] = rk;
      int tk = mf * 16 + (lg << 2) + r;
      *(u16*)(Kn + tk * 80 + lc * 2) = f2bf(v0 * rk);
      *(u16*)(Kn + tk * 80 + (16 + lc) * 2) = f2bf(v1 * rk);
    }
  MEMBAR();
#pragma unroll
  for (int i = 0; i < 4; ++i)
    kf_hi[i] = *(const short8*)(Kn + (i * 16 + lc) * 80 + (lg << 4));
  MEMBAR();
#pragma unroll
  for (int mf = 0; mf < 4; ++mf)
#pragma unroll
    for (int r = 0; r < 4; ++r) {
      int tk = mf * 16 + (lg << 2) + r;
      float s0 = macc[mf][0][r] * rnrm[mf][r];
      float s1 = macc[mf][1][r] * rnrm[mf][r];
      *(u16*)(Kn + tk * 80 + lc * 2) = f2bf(s0 - bf2f(f2bf(s0)));
      *(u16*)(Kn + tk * 80 + (16 + lc) * 2) = f2bf(s1 - bf2f(f2bf(s1)));
    }
  MEMBAR();
#pragma unroll
  for (int i = 0; i < 4; ++i)
    kf_lo[i] = *(const short8*)(Kn + (i * 16 + lc) * 80 + (lg << 4));
  MEMBAR();

  // ---- Q: project+bias, normalize*scale; hi -> frags; lo -> frags ----
  qkv_mm(Elds, qwb, 0, h, lc, lg, macc);
  {
    float qb0 = qkv_b[h * 32 + lc], qb1 = qkv_b[h * 32 + 16 + lc];
#pragma unroll
    for (int mf = 0; mf < 4; ++mf)
#pragma unroll
      for (int r = 0; r < 4; ++r) {
        float v0 = macc[mf][0][r] + qb0, v1 = macc[mf][1][r] + qb1;
        macc[mf][0][r] = v0;
        macc[mf][1][r] = v1;
        float ss = v0 * v0 + v1 * v1;
        ss += __shfl_xor(ss, 1);
        ss += __shfl_xor(ss, 2);
        ss += __shfl_xor(ss, 4);
        ss += __shfl_xor(ss, 8);
        float rq = scale / fmaxf(sqrtf(ss), 1e-12f);
        rnrm[mf][r] = rq;
        int tk = mf * 16 + (lg << 2) + r;
        *(u16*)(Qn + tk * 80 + lc * 2) = f2bf(v0 * rq);
        *(u16*)(Qn + tk * 80 + (16 + lc) * 2) = f2bf(v1 * rq);
      }
    MEMBAR();
#pragma unroll
    for (int i = 0; i < 4; ++i)
      qf_hi[i] = *(const short8*)(Qn + (i * 16 + lc) * 80 + (lg << 4));
    MEMBAR();
#pragma unroll
    for (int mf = 0; mf < 4; ++mf)
#pragma unroll
      for (int r = 0; r < 4; ++r) {
        int tk = mf * 16 + (lg << 2) + r;
        float s0 = macc[mf][0][r] * rnrm[mf][r];
        float s1 = macc[mf][1][r] * rnrm[mf][r];
        *(u16*)(Qn + tk * 80 + lc * 2) = f2bf(s0 - bf2f(f2bf(s0)));
        *(u16*)(Qn + tk * 80 + (16 + lc) * 2) = f2bf(s1 - bf2f(f2bf(s1)));
      }
    MEMBAR();
#pragma unroll
    for (int i = 0; i < 4; ++i)
      qf_lo[i] = *(const short8*)(Qn + (i * 16 + lc) * 80 + (lg << 4));
    MEMBAR();
  }

  // ---- V: project + bias, hold in regs across the barrier ----
  qkv_mm(Elds, qwb, 512, h, lc, lg, macc);
  float vb0 = qkv_b[512 + h * 32 + lc], vb1 = qkv_b[512 + h * 32 + 16 + lc];
  __syncthreads();  // all E reads done; E region becomes Vt
#pragma unroll
  for (int mf = 0; mf < 4; ++mf)
#pragma unroll
    for (int r = 0; r < 4; ++r) {
      int tk = mf * 16 + (lg << 2) + r;
      *(u16*)(Vt + lc * 144 + tk * 2) = f2bf(macc[mf][0][r] + vb0);
      *(u16*)(Vt + (16 + lc) * 144 + tk * 2) = f2bf(macc[mf][1][r] + vb1);
    }
  MEMBAR();

  // ---- S^T = Kn @ Qs^T with hi/lo: fp32-accurate logits ----
  floatx4 zz = {0.f, 0.f, 0.f, 0.f};
  floatx4 S[4][4];
#pragma unroll
  for (int mi = 0; mi < 4; ++mi)
#pragma unroll
    for (int ni = 0; ni < 4; ++ni) {
      floatx4 a = __builtin_amdgcn_mfma_f32_16x16x32_bf16(kf_lo[mi], qf_hi[ni], zz, 0, 0, 0);
      a = __builtin_amdgcn_mfma_f32_16x16x32_bf16(kf_hi[mi], qf_lo[ni], a, 0, 0, 0);
      S[mi][ni] = __builtin_amdgcn_mfma_f32_16x16x32_bf16(kf_hi[mi], qf_hi[ni], a, 0, 0, 0);
    }

  const float* bh = bias_t + h * 4096;
  float den[4] = {0.f, 0.f, 0.f, 0.f};
#pragma unroll
  for (int mi = 0; mi < 4; ++mi) {
    int mb = mi * 16 + (lg << 2);
#pragma unroll
    for (int ni = 0; ni < 4; ++ni) {
      int nn = ni * 16 + lc;
#pragma unroll
      for (int r = 0; r < 4; ++r) {
        float e = __expf(S[mi][ni][r] + bh[(mb + r) * 64 + nn]);
        S[mi][ni][r] = e;
        den[ni] += e;
      }
    }
  }
#pragma unroll
  for (int ni = 0; ni < 4; ++ni) {
    den[ni] += __shfl_xor(den[ni], 16);
    den[ni] += __shfl_xor(den[ni], 32);
    den[ni] = 1.f / den[ni];
  }
#pragma unroll
  for (int ni = 0; ni < 4; ++ni)
#pragma unroll
    for (int mi = 0; mi < 4; ++mi) {
      uint2 v;
      v.x = pack2(S[mi][ni][0] * den[ni], S[mi][ni][1] * den[ni]);
      v.y = pack2(S[mi][ni][2] * den[ni], S[mi][ni][3] * den[ni]);
      *(uint2*)(Pt + (ni * 16 + lc) * 144 + mi * 32 + (lg << 3)) = v;
    }
  MEMBAR();
  short8 vf[2][2];
#pragma unroll
  for (int ks = 0; ks < 2; ++ks)
#pragma unroll
    for (int db = 0; db < 2; ++db)
      vf[ks][db] = *(const short8*)(Vt + (db * 16 + lc) * 144 + ks * 64 + (lg << 4));
  floatx4 O[4][2];
#pragma unroll
  for (int nb = 0; nb < 4; ++nb) {
    O[nb][0] = zz;
    O[nb][1] = zz;
  }
#pragma unroll
  for (int nb = 0; nb < 4; ++nb) {
    short8 pf0 = *(const short8*)(Pt + (nb * 16 + lc) * 144 + (lg << 4));
    short8 pf1 = *(const short8*)(Pt + (nb * 16 + lc) * 144 + 64 + (lg << 4));
    O[nb][0] = __builtin_amdgcn_mfma_f32_16x16x32_bf16(pf0, vf[0][0], O[nb][0], 0, 0, 0);
    O[nb][0] = __builtin_amdgcn_mfma_f32_16x16x32_bf16(pf1, vf[1][0], O[nb][0], 0, 0, 0);
    O[nb][1] = __builtin_amdgcn_mfma_f32_16x16x32_bf16(pf0, vf[0][1], O[nb][1], 0, 0, 0);
    O[nb][1] = __builtin_amdgcn_mfma_f32_16x16x32_bf16(pf1, vf[1][1], O[nb][1], 0, 0, 0);
  }
  MEMBAR();
#pragma unroll
  for (int nb = 0; nb < 4; ++nb)
#pragma unroll
    for (int r = 0; r < 4; ++r) {
      int n = nb * 16 + (lg << 2) + r;
      *(u16*)(Ol + n * 72 + lc * 2) = f2bf(O[nb][0][r]);
      *(u16*)(Ol + n * 72 + (16 + lc) * 2) = f2bf(O[nb][1][r]);
    }
  MEMBAR();
  u32 ov[16];
#pragma unroll
  for (int j = 0; j < 16; ++j) ov[j] = *(const u32*)(Ol + l * 72 + j * 4);
  uint4* op = (uint4*)(ao + (size_t)(wid * 64 + l) * 256 + h * 32);
#pragma unroll
  for (int q4 = 0; q4 < 4; ++q4) {
    uint4 v;
    v.x = ov[q4 * 4 + 0];
    v.y = ov[q4 * 4 + 1];
    v.z = ov[q4 * 4 + 2];
    v.w = ov[q4 * 4 + 3];
    op[q4] = v;
  }
}

// ---------------- LN1: SBF = bf16( EBF + LN(P) ), vectorized (R4) -----------
__global__ __launch_bounds__(256) void ln1v_kernel(
    const u16* __restrict__ pin, const u16* __restrict__ ebf,
    u16* __restrict__ sbf, const float* __restrict__ g,
    const float* __restrict__ bb) {
  int tid = threadIdx.x;
  int bid = blockIdx.x;  // 1024 = b(4) x 256 groups of 64 pixels
  int b = bid >> 8, hw0 = (bid & 255) << 6;
  int i = tid >> 2, qq = tid & 3;
  int hw = hw0 + i;
  int him = hw >> 7, wim = hw & 127;
  int wid = b * 256 + (him >> 3) * 16 + (wim >> 3);
  int t = wid * 64 + (him & 7) * 8 + (wim & 7);
  size_t pbase = (size_t)t * 256 + qq * 64;
  size_t ebase = ((size_t)(b * HW + hw)) * 256 + qq * 64;
  float v[64];
  float s1 = 0.f, s2 = 0.f;
#pragma unroll
  for (int j = 0; j < 8; ++j) {
    uint4 u = *(const uint4*)(pin + pbase + j * 8);
    u32 ua[4] = {u.x, u.y, u.z, u.w};
#pragma unroll
    for (int k = 0; k < 4; ++k) {
      float a = bflo(ua[k]), c = bfhi(ua[k]);
      v[j * 8 + 2 * k] = a;
      v[j * 8 + 2 * k + 1] = c;
      s1 += a + c;
      s2 += a * a + c * c;
    }
  }
  s1 += __shfl_xor(s1, 1);
  s1 += __shfl_xor(s1, 2);
  s2 += __shfl_xor(s2, 1);
  s2 += __shfl_xor(s2, 2);
  float mean = s1 * (1.f / 256.f);
  float var = s2 * (1.f / 256.f) - mean * mean;
  float rs = rsqrtf(var + 1e-5f);
#pragma unroll
  for (int j = 0; j < 8; ++j) {
    uint4 u = *(const uint4*)(ebf + ebase + j * 8);
    u32 ua[4] = {u.x, u.y, u.z, u.w};
    uint4 o;
    u32 ow[4];
#pragma unroll
    for (int k = 0; k < 4; ++k) {
      int c = qq * 64 + j * 8 + 2 * k;
      float o0 = bflo(ua[k]) + (v[j * 8 + 2 * k] - mean) * rs * g[c] + bb[c];
      float o1 = bfhi(ua[k]) + (v[j * 8 + 2 * k + 1] - mean) * rs * g[c + 1] + bb[c + 1];
      ow[k] = pack2(o0, o1);
    }
    o.x = ow[0]; o.y = ow[1]; o.z = ow[2]; o.w = ow[3];
    *(uint4*)(sbf + ebase + j * 8) = o;
  }
}

// ---------------- LN2 + residual + NHWC->NCHW store fused (R4) --------------
__global__ __launch_bounds__(256) void ln2t_kernel(
    const u16* __restrict__ h2, const u16* __restrict__ sbf,
    const float* __restrict__ g, const float* __restrict__ bb,
    float* __restrict__ outp) {
  __shared__ float tile[64][257];
  int tid = threadIdx.x;
  int bid = blockIdx.x;  // 1024 = b(4) x 256 groups
  int b = bid >> 8, hw0 = (bid & 255) << 6;
  int i = tid >> 2, qq = tid & 3;
  size_t base = ((size_t)(b * HW + hw0 + i)) * 256 + qq * 64;
  float v[64];
  float s1 = 0.f, s2 = 0.f;
#pragma unroll
  for (int j = 0; j < 8; ++j) {
    uint4 u = *(const uint4*)(h2 + base + j * 8);
    u32 ua[4] = {u.x, u.y, u.z, u.w};
#pragma unroll
    for (int k = 0; k < 4; ++k) {
      float a = bflo(ua[k]), c = bfhi(ua[k]);
      v[j * 8 + 2 * k] = a;
      v[j * 8 + 2 * k + 1] = c;
      s1 += a + c;
      s2 += a * a + c * c;
    }
  }
  s1 += __shfl_xor(s1, 1);
  s1 += __shfl_xor(s1, 2);
  s2 += __shfl_xor(s2, 1);
  s2 += __shfl_xor(s2, 2);
  float mean = s1 * (1.f / 256.f);
  float var = s2 * (1.f / 256.f) - mean * mean;
  float rs = rsqrtf(var + 1e-5f);
#pragma unroll
  for (int j = 0; j < 8; ++j) {
    uint4 u = *(const uint4*)(sbf + base + j * 8);
    u32 ua[4] = {u.x, u.y, u.z, u.w};
#pragma unroll
    for (int k = 0; k < 4; ++k) {
      int c = qq * 64 + j * 8 + 2 * k;
      tile[i][c] = bflo(ua[k]) + (v[j * 8 + 2 * k] - mean) * rs * g[c] + bb[c];
      tile[i][c + 1] = bfhi(ua[k]) + (v[j * 8 + 2 * k + 1] - mean) * rs * g[c + 1] + bb[c + 1];
    }
  }
  __syncthreads();
  int pl = tid & 63, cq = tid >> 6;
#pragma unroll 8
  for (int cc = 0; cc < 64; ++cc) {
    int c = cq * 64 + cc;
    outp[((size_t)(b * 256 + c)) * HW + hw0 + pl] = tile[pl][c];
  }
}

// ---------------------------------------------------------------------------
extern "C" void kernel_launch(void* const* d_in, const int* in_sizes, int n_in,
                              void* d_out, int out_size, void* d_ws, size_t ws_size,
                              hipStream_t stream) {
  const float* x        = (const float*)d_in[0];
  const float* w_stem   = (const float*)d_in[1];
  const float* s_stem   = (const float*)d_in[2];
  const float* b_stem   = (const float*)d_in[3];
  const float* w_blk    = (const float*)d_in[4];
  const float* s_blk    = (const float*)d_in[5];
  const float* b_blk    = (const float*)d_in[6];
  const float* norm1_g  = (const float*)d_in[7];
  const float* norm1_b  = (const float*)d_in[8];
  const float* qkv_w    = (const float*)d_in[9];
  const float* qkv_b    = (const float*)d_in[10];
  const float* proj_w   = (const float*)d_in[11];
  const float* proj_b   = (const float*)d_in[12];
  const float* logit_sc = (const float*)d_in[13];
  const float* cpb_w1   = (const float*)d_in[14];
  const float* cpb_b1   = (const float*)d_in[15];
  const float* cpb_w2   = (const float*)d_in[16];
  const float* norm2_g  = (const float*)d_in[17];
  const float* norm2_b  = (const float*)d_in[18];
  const float* mlp_w1   = (const float*)d_in[19];
  const float* mlp_b1   = (const float*)d_in[20];
  const float* mlp_w2   = (const float*)d_in[21];
  const float* mlp_b2   = (const float*)d_in[22];
  float* out = (float*)d_out;
  float* ws = (float*)d_ws;
  (void)in_sizes; (void)n_in; (void)out_size; (void)ws_size;

  // ---- workspace regions (floats) ----
  float* R0 = ws;                  // 16,777,216
  float* R1 = ws + 16777216;       // 16,777,216
  float* R2 = ws + 33554432;       // 16,777,216
  float* TAIL = ws + 50331648;
  u16* WTC  = (u16*)TAIL;                    // conv blk weights bf16
  u16* WTS  = (u16*)(TAIL + 73728);          // stem weights bf16
  u16* QWB  = (u16*)(TAIL + 81920);          // qkv_w bf16 [768][256]
  u16* PWB  = (u16*)(TAIL + 180224);         // proj_w bf16
  u16* M1WB = (u16*)(TAIL + 212992);
  u16* M2WB = (u16*)(TAIL + 245760);
  float* BPRE = TAIL + 278528;
  float* BFT  = TAIL + 280576;               // bias_t[8][64][64]

  // phase overlays (R4-verified lifetimes):
  u16* XT  = (u16*)R2;               // [65536][128] bf16, dead after stem gemm
  u16* EBF = (u16*)(R2 + 8388608);   // [65536][256] bf16 NHWC e; lives to LN1
  u16* T1  = (u16*)R1;               // conv intermediates
  u16* T2  = (u16*)(R1 + 2097152);
  u16* AO  = (u16*)R0;               // attn out token-major [65536][256]
  u16* P   = (u16*)(R0 + 8388608);   // proj out token-major
  u16* SBF = (u16*)R0;               // S bf16 pixel-major (over dead AO)
  u16* Hb  = (u16*)R2;               // mlp hidden (over dead XT)
  u16* H2  = (u16*)(R0 + 8388608);   // mlp out (over dead P)

  // ---- param prep ----
  repack_kernel<<<640, 256, 0, stream>>>(w_blk, s_blk, w_stem, s_stem, WTC, WTS);
  castw_kernel<<<768, 256, 0, stream>>>(qkv_w, QWB, 196608);
  castw_kernel<<<256, 256, 0, stream>>>(proj_w, PWB, 65536);
  castw_kernel<<<256, 256, 0, stream>>>(mlp_w1, M1WB, 65536);
  castw_kernel<<<256, 256, 0, stream>>>(mlp_w2, M2WB, 65536);
  cpb_mlp_kernel<<<225, 512, 0, stream>>>(cpb_w1, cpb_b1, cpb_w2, BPRE);
  cpb_expand_kernel<<<16, 256, 0, stream>>>(BPRE, BFT);

  // ---- input transpose + stem (1x1 conv = GEMM, SiLU) -> EBF ch 128..255 ----
  transpose_in_kernel<<<2048, 256, 0, stream>>>(x, XT);
  dim3 gs(512, 2);
  gemm_bf16_kernel<<<gs, 256, 0, stream>>>(XT, WTS, b_stem, EBF + 128, 128, 256, 2);

  // ---- ELAN 3x3 convs (bf16 MFMA implicit GEMM) ----
  dim3 cgrid(16, 16, 4);
  conv3x3_mfma_kernel<<<cgrid, 256, 0, stream>>>(EBF + 128, 256, T1, 64, WTC, b_blk);
  conv3x3_mfma_kernel<<<cgrid, 256, 0, stream>>>(T1, 64, EBF + 64, 256, WTC + 9 * 4096, b_blk + 64);
  conv3x3_mfma_kernel<<<cgrid, 256, 0, stream>>>(EBF + 64, 256, T2, 64, WTC + 18 * 4096, b_blk + 128);
  conv3x3_mfma_kernel<<<cgrid, 256, 0, stream>>>(T2, 64, EBF, 256, WTC + 27 * 4096, b_blk + 192);

  // ---- fused qkv + window attention (hi/lo QK^T) ----
  attn_fused_kernel<<<2048, 256, 0, stream>>>(EBF, QWB, qkv_b, logit_sc, BFT, AO);

  // ---- proj + LN1 + MLP + LN2(+transpose), R4-verified kernels ----
  dim3 g4(512, 4);
  gemm_bf16_kernel<<<g4, 256, 0, stream>>>(AO, PWB, proj_b, P, 256, 256, 0);
  ln1v_kernel<<<1024, 256, 0, stream>>>(P, EBF, SBF, norm1_g, norm1_b);
  gemm_bf16_kernel<<<g4, 256, 0, stream>>>(SBF, M1WB, mlp_b1, Hb, 256, 256, 1);
  gemm_bf16_kernel<<<g4, 256, 0, stream>>>(Hb, M2WB, mlp_b2, H2, 256, 256, 0);
  ln2t_kernel<<<1024, 256, 0, stream>>>(H2, SBF, norm2_g, norm2_b, out);
}